// Round 1
// baseline (1958.389 us; speedup 1.0000x reference)
//
#include <hip/hip_runtime.h>
#include <hip/hip_bf16.h>

using u16 = unsigned short;
using u32 = unsigned int;

typedef __attribute__((ext_vector_type(8))) short bf8;   // 8 x bf16 bits (4 VGPR)
typedef __attribute__((ext_vector_type(4))) float f4;    // MFMA acc
typedef __attribute__((ext_vector_type(4))) u16  us4;

#define DEV static __device__ __forceinline__

DEV float bf2f(u16 u) { return __uint_as_float(((u32)u) << 16); }
DEV u16 f2bf(float f) {
    u32 x = __float_as_uint(f);
    x += 0x7FFFu + ((x >> 16) & 1u);          // RNE
    return (u16)(x >> 16);
}
DEV float tanhf_fast(float x) {               // tanh = 1 - 2/(e^{2x}+1)
    float e = __expf(2.0f * x);
    return 1.0f - 2.0f / (e + 1.0f);
}
DEV f4 MFMA(bf8 a, bf8 b, f4 c) {
    return __builtin_amdgcn_mfma_f32_16x16x32_bf16(a, b, c, 0, 0, 0);
}

// ---------------- constants ----------------
// D=1024 E=2048 S_DIM=128 C=256 SRC=4096 G=16 B=8, M = B*SRC = 32768 rows
// GEMM row order r = b*4096 + s  (s = g*256 + c)

// ---------------- workspace layout (bytes) ----------------
#define WS_XB    ((size_t)0)                    // bf16 x, layout [s][b][d] (same as value)   64 MiB
#define WS_WXST  ((size_t)67108864)             // WxsT [128][1024]                           256 KiB
#define WS_WVET  ((size_t)67371008)             // WveT [2048][1024]                          4 MiB
#define WS_WUET  ((size_t)71565312)             // WueT [2048][1024]                          4 MiB
#define WS_WODT  ((size_t)75759616)             // WodT [1024][2048]                          4 MiB
#define WS_Z     ((size_t)79953920)             // z bf16 [B*4096][128]                       8 MiB
#define WS_VT    ((size_t)88342528)             // vT bf16 [B][2048][4096]                    128 MiB
#define WS_KVT   ((size_t)222560256)            // kvT bf16 [B][2048][128]                    4 MiB
#define WS_A     ((size_t)226754560)            // a bf16 [128][256][256]                     16 MiB
#define WS_T1    ((size_t)243531776)            // t1 bf16 [32768][2048]                      128 MiB
#define WS_KVF   ((size_t)377749504)            // kvF f32 [B][2048][128]                     8 MiB
// total 386,138,112 bytes

// ---------------- conversion kernels ----------------
__global__ void k_cvt_x(const float* __restrict__ src, u16* __restrict__ dst, int n) {
    int i = (blockIdx.x * blockDim.x + threadIdx.x) * 4;
    if (i < n) {
        float4 v = *reinterpret_cast<const float4*>(src + i);
        us4 o; o[0] = f2bf(v.x); o[1] = f2bf(v.y); o[2] = f2bf(v.z); o[3] = f2bf(v.w);
        *reinterpret_cast<us4*>(dst + i) = o;
    }
}

// src[R][C] f32 -> dst[C][R] bf16
__global__ void k_transpose(const float* __restrict__ src, u16* __restrict__ dst, int R, int C) {
    __shared__ u16 tile[32][33];
    int tx = threadIdx.x & 31, ty = threadIdx.x >> 5;   // 256 thr: 32x8
    int r0 = blockIdx.y * 32, c0 = blockIdx.x * 32;
    #pragma unroll
    for (int rr = ty; rr < 32; rr += 8)
        tile[rr][tx] = f2bf(src[(size_t)(r0 + rr) * C + c0 + tx]);
    __syncthreads();
    #pragma unroll
    for (int cc = ty; cc < 32; cc += 8)
        dst[(size_t)(c0 + cc) * R + r0 + tx] = tile[tx][cc];
}

// ---------------- z = tanh(x @ Wxs + bxs), bf16 [32768][128] ----------------
__global__ __launch_bounds__(256) void k_zgemm(const u16* __restrict__ xb, const u16* __restrict__ WxsT,
                                               const float* __restrict__ bxs, u16* __restrict__ z) {
    const int lane = threadIdx.x & 63, wid = threadIdx.x >> 6;
    const int ln = lane & 15, lh = lane >> 4;
    const int mbase = blockIdx.x * 128 + wid * 32;      // wave: 32 rows x 128 cols
    f4 acc[2][8] = {};
    const u16* ar[2];
    #pragma unroll
    for (int mt = 0; mt < 2; mt++) {
        int r = mbase + mt * 16 + ln;
        int bb = r >> 12, s = r & 4095;
        ar[mt] = xb + ((size_t)(s * 8 + bb) << 10);
    }
    const u16* br[8];
    #pragma unroll
    for (int nt = 0; nt < 8; nt++) br[nt] = WxsT + ((size_t)(nt * 16 + ln) << 10);
    for (int kk = 0; kk < 1024; kk += 32) {
        int k0 = kk + lh * 8;
        bf8 a[2], b[8];
        #pragma unroll
        for (int mt = 0; mt < 2; mt++) a[mt] = *reinterpret_cast<const bf8*>(ar[mt] + k0);
        #pragma unroll
        for (int nt = 0; nt < 8; nt++) b[nt] = *reinterpret_cast<const bf8*>(br[nt] + k0);
        #pragma unroll
        for (int mt = 0; mt < 2; mt++)
            #pragma unroll
            for (int nt = 0; nt < 8; nt++)
                acc[mt][nt] = MFMA(a[mt], b[nt], acc[mt][nt]);
    }
    #pragma unroll
    for (int mt = 0; mt < 2; mt++)
        #pragma unroll
        for (int nt = 0; nt < 8; nt++) {
            int col = nt * 16 + ln;
            float bias = bxs[col];
            int r0 = mbase + mt * 16 + lh * 4;
            #pragma unroll
            for (int rg = 0; rg < 4; rg++)
                z[((size_t)(r0 + rg) << 7) + col] = f2bf(tanhf_fast(acc[mt][nt][rg] + bias));
        }
}

// ---------------- vT = tanh(x @ Wve + bve)^T : bf16 [B][2048][4096] ----------------
__global__ __launch_bounds__(256) void k_vgemm(const u16* __restrict__ xb, const u16* __restrict__ WveT,
                                               const float* __restrict__ bve, u16* __restrict__ vT) {
    const int lane = threadIdx.x & 63, wid = threadIdx.x >> 6;
    const int ln = lane & 15, lh = lane >> 4;
    const int wm = wid >> 1, wn = wid & 1;
    const int mbase = blockIdx.x * 128 + wm * 64;
    const int nbase = blockIdx.y * 128 + wn * 64;
    f4 acc[4][4] = {};
    const u16* ar[4];
    #pragma unroll
    for (int mt = 0; mt < 4; mt++) {
        int r = mbase + mt * 16 + ln;
        ar[mt] = xb + ((size_t)((r & 4095) * 8 + (r >> 12)) << 10);
    }
    const u16* br[4];
    #pragma unroll
    for (int nt = 0; nt < 4; nt++) br[nt] = WveT + ((size_t)(nbase + nt * 16 + ln) << 10);
    for (int kk = 0; kk < 1024; kk += 32) {
        int k0 = kk + lh * 8;
        bf8 a[4], b[4];
        #pragma unroll
        for (int mt = 0; mt < 4; mt++) a[mt] = *reinterpret_cast<const bf8*>(ar[mt] + k0);
        #pragma unroll
        for (int nt = 0; nt < 4; nt++) b[nt] = *reinterpret_cast<const bf8*>(br[nt] + k0);
        #pragma unroll
        for (int mt = 0; mt < 4; mt++)
            #pragma unroll
            for (int nt = 0; nt < 4; nt++)
                acc[mt][nt] = MFMA(a[mt], b[nt], acc[mt][nt]);
    }
    #pragma unroll
    for (int mt = 0; mt < 4; mt++)
        #pragma unroll
        for (int nt = 0; nt < 4; nt++) {
            int e = nbase + nt * 16 + ln;
            float bias = bve[e];
            int r0 = mbase + mt * 16 + lh * 4;
            int bb = r0 >> 12, s0 = r0 & 4095;       // 4 consecutive s, same b
            us4 p;
            #pragma unroll
            for (int rg = 0; rg < 4; rg++) p[rg] = f2bf(tanhf_fast(acc[mt][nt][rg] + bias));
            *reinterpret_cast<us4*>(vT + ((size_t)(bb * 2048 + e) << 12) + s0) = p;
        }
}

// ---------------- kvF[b][e][s] += sum_c vT[b][e][c] * (z[b,c,:]*g3+b3)[s]  (K-split x4, atomics) ----------------
__global__ __launch_bounds__(256) void k_kv(const u16* __restrict__ vT, const u16* __restrict__ z,
                                            const float* __restrict__ gamma, const float* __restrict__ beta,
                                            float* __restrict__ kvF) {
    const int lane = threadIdx.x & 63, wid = threadIdx.x >> 6;
    const int ln = lane & 15, lh = lane >> 4;
    const int wm = wid >> 1, wn = wid & 1;
    const int b = blockIdx.y;
    const int mbase = blockIdx.x * 128 + wm * 64;    // e
    const int nbase = wn * 64;                       // s
    const int kbase = blockIdx.z * 1024;             // c segment
    const float* g3 = gamma + 384;
    const float* b3 = beta + 384;
    f4 acc[4][4] = {};
    const u16* ar[4];
    #pragma unroll
    for (int mt = 0; mt < 4; mt++)
        ar[mt] = vT + ((size_t)(b * 2048 + mbase + mt * 16 + ln) << 12);
    int scol[4]; float gs[4], bs[4];
    #pragma unroll
    for (int nt = 0; nt < 4; nt++) {
        scol[nt] = nbase + nt * 16 + ln;
        gs[nt] = g3[scol[nt]]; bs[nt] = b3[scol[nt]];
    }
    const u16* zb = z + ((size_t)(b * 4096) << 7);
    for (int kk = kbase; kk < kbase + 1024; kk += 32) {
        int k0 = kk + lh * 8;
        bf8 a[4], bb[4];
        #pragma unroll
        for (int mt = 0; mt < 4; mt++) a[mt] = *reinterpret_cast<const bf8*>(ar[mt] + k0);
        #pragma unroll
        for (int nt = 0; nt < 4; nt++) {
            #pragma unroll
            for (int j = 0; j < 8; j++) {
                u16 zv = zb[((size_t)(k0 + j) << 7) + scol[nt]];
                bb[nt][j] = (short)f2bf(bf2f(zv) * gs[nt] + bs[nt]);
            }
        }
        #pragma unroll
        for (int mt = 0; mt < 4; mt++)
            #pragma unroll
            for (int nt = 0; nt < 4; nt++)
                acc[mt][nt] = MFMA(a[mt], bb[nt], acc[mt][nt]);
    }
    #pragma unroll
    for (int mt = 0; mt < 4; mt++)
        #pragma unroll
        for (int nt = 0; nt < 4; nt++) {
            int r0 = mbase + mt * 16 + lh * 4;       // e rows
            #pragma unroll
            for (int rg = 0; rg < 4; rg++)
                atomicAdd(&kvF[((size_t)(b * 2048 + r0 + rg) << 7) + scol[nt]], acc[mt][nt][rg]);
        }
}

__global__ void k_kvcvt(const float* __restrict__ kvF, u16* __restrict__ kvT, int n) {
    int i = (blockIdx.x * blockDim.x + threadIdx.x) * 4;
    if (i < n) {
        float4 v = *reinterpret_cast<const float4*>(kvF + i);
        us4 o; o[0] = f2bf(v.x); o[1] = f2bf(v.y); o[2] = f2bf(v.z); o[3] = f2bf(v.w);
        *reinterpret_cast<us4*>(kvT + i) = o;
    }
}

// ---------------- a = relu(q_quad @ k_quad^T + rel_bias)^2 : bf16 [128][256][256] ----------------
__global__ __launch_bounds__(256) void k_a(const u16* __restrict__ z, const float* __restrict__ gamma,
                                           const float* __restrict__ beta, const float* __restrict__ rel_bias,
                                           u16* __restrict__ a_out) {
    const int lane = threadIdx.x & 63, wid = threadIdx.x >> 6;
    const int ln = lane & 15, lh = lane >> 4;
    const int wm = wid >> 1, wn = wid & 1;
    const int ci = blockIdx.y;
    const int b = ci >> 4, g = ci & 15;
    const int rowbase = (b << 12) + (g << 8);
    const int qbase = blockIdx.x * 128 + wm * 64;    // q rows within chunk
    const int nbase = wn * 128;                      // key cols within chunk
    const float* g0 = gamma,       *b0 = beta;
    const float* g1 = gamma + 128, *b1 = beta + 128;
    f4 acc[4][8] = {};
    const u16* qr[4];
    #pragma unroll
    for (int mt = 0; mt < 4; mt++) qr[mt] = z + ((size_t)(rowbase + qbase + mt * 16 + ln) << 7);
    const u16* kr[8];
    #pragma unroll
    for (int nt = 0; nt < 8; nt++) kr[nt] = z + ((size_t)(rowbase + nbase + nt * 16 + ln) << 7);
    for (int kk = 0; kk < 128; kk += 32) {
        int k0 = kk + lh * 8;
        float gq[8], bq[8], gk[8], bk[8];
        #pragma unroll
        for (int j = 0; j < 8; j++) { gq[j] = g0[k0 + j]; bq[j] = b0[k0 + j]; gk[j] = g1[k0 + j]; bk[j] = b1[k0 + j]; }
        bf8 aq[4], ak[8];
        #pragma unroll
        for (int mt = 0; mt < 4; mt++) {
            bf8 zz = *reinterpret_cast<const bf8*>(qr[mt] + k0);
            #pragma unroll
            for (int j = 0; j < 8; j++) aq[mt][j] = (short)f2bf(bf2f((u16)zz[j]) * gq[j] + bq[j]);
        }
        #pragma unroll
        for (int nt = 0; nt < 8; nt++) {
            bf8 zz = *reinterpret_cast<const bf8*>(kr[nt] + k0);
            #pragma unroll
            for (int j = 0; j < 8; j++) ak[nt][j] = (short)f2bf(bf2f((u16)zz[j]) * gk[j] + bk[j]);
        }
        #pragma unroll
        for (int mt = 0; mt < 4; mt++)
            #pragma unroll
            for (int nt = 0; nt < 8; nt++)
                acc[mt][nt] = MFMA(aq[mt], ak[nt], acc[mt][nt]);
    }
    #pragma unroll
    for (int nt = 0; nt < 8; nt++) {
        int key = nbase + nt * 16 + ln;
        float rb = rel_bias[key];
        #pragma unroll
        for (int mt = 0; mt < 4; mt++) {
            int r0 = qbase + mt * 16 + lh * 4;
            #pragma unroll
            for (int rg = 0; rg < 4; rg++) {
                float v = acc[mt][nt][rg] + rb;
                v = fmaxf(v, 0.0f); v = v * v;
                a_out[((size_t)ci << 16) + ((size_t)(r0 + rg) << 8) + key] = f2bf(v);
            }
        }
    }
}

// ---------------- t1 = q_lin @ kv + a @ v : bf16 [32768][2048] ----------------
__global__ __launch_bounds__(256) void k_t1(const u16* __restrict__ z, const u16* __restrict__ a_in,
                                            const u16* __restrict__ vT, const u16* __restrict__ kvT,
                                            const float* __restrict__ gamma, const float* __restrict__ beta,
                                            u16* __restrict__ t1) {
    const int lane = threadIdx.x & 63, wid = threadIdx.x >> 6;
    const int ln = lane & 15, lh = lane >> 4;
    const int wm = wid >> 1, wn = wid & 1;
    const int ci = blockIdx.y;
    const int b = ci >> 4, g = ci & 15;
    const int rowbase = (b << 12) + (g << 8);
    const int ebase = blockIdx.x * 128 + wn * 64;
    const int qbase = wm * 128;                      // wave: 128 q x 64 e
    f4 acc[8][4] = {};
    // phase 1: v_lin = q_lin @ kvT^T   (K = 128 s)
    {
        const float* g2 = gamma + 256, *b2 = beta + 256;
        const u16* qr[8];
        #pragma unroll
        for (int mt = 0; mt < 8; mt++) qr[mt] = z + ((size_t)(rowbase + qbase + mt * 16 + ln) << 7);
        const u16* kvr[4];
        #pragma unroll
        for (int nt = 0; nt < 4; nt++) kvr[nt] = kvT + ((size_t)(b * 2048 + ebase + nt * 16 + ln) << 7);
        for (int kk = 0; kk < 128; kk += 32) {
            int k0 = kk + lh * 8;
            float gq[8], bq[8];
            #pragma unroll
            for (int j = 0; j < 8; j++) { gq[j] = g2[k0 + j]; bq[j] = b2[k0 + j]; }
            bf8 aq[8], bv[4];
            #pragma unroll
            for (int mt = 0; mt < 8; mt++) {
                bf8 zz = *reinterpret_cast<const bf8*>(qr[mt] + k0);
                #pragma unroll
                for (int j = 0; j < 8; j++) aq[mt][j] = (short)f2bf(bf2f((u16)zz[j]) * gq[j] + bq[j]);
            }
            #pragma unroll
            for (int nt = 0; nt < 4; nt++) bv[nt] = *reinterpret_cast<const bf8*>(kvr[nt] + k0);
            #pragma unroll
            for (int mt = 0; mt < 8; mt++)
                #pragma unroll
                for (int nt = 0; nt < 4; nt++)
                    acc[mt][nt] = MFMA(aq[mt], bv[nt], acc[mt][nt]);
        }
    }
    // phase 2: v_quad = a @ v   (K = 256 keys)
    {
        const u16* arow[8];
        #pragma unroll
        for (int mt = 0; mt < 8; mt++)
            arow[mt] = a_in + ((size_t)ci << 16) + ((size_t)(qbase + mt * 16 + ln) << 8);
        const u16* vr[4];
        #pragma unroll
        for (int nt = 0; nt < 4; nt++)
            vr[nt] = vT + ((size_t)(b * 2048 + ebase + nt * 16 + ln) << 12) + (g << 8);
        for (int kk = 0; kk < 256; kk += 32) {
            int k0 = kk + lh * 8;
            bf8 aa[8], bb[4];
            #pragma unroll
            for (int mt = 0; mt < 8; mt++) aa[mt] = *reinterpret_cast<const bf8*>(arow[mt] + k0);
            #pragma unroll
            for (int nt = 0; nt < 4; nt++) bb[nt] = *reinterpret_cast<const bf8*>(vr[nt] + k0);
            #pragma unroll
            for (int mt = 0; mt < 8; mt++)
                #pragma unroll
                for (int nt = 0; nt < 4; nt++)
                    acc[mt][nt] = MFMA(aa[mt], bb[nt], acc[mt][nt]);
        }
    }
    #pragma unroll
    for (int mt = 0; mt < 8; mt++)
        #pragma unroll
        for (int nt = 0; nt < 4; nt++) {
            int e = ebase + nt * 16 + ln;
            int r0 = rowbase + qbase + mt * 16 + lh * 4;
            #pragma unroll
            for (int rg = 0; rg < 4; rg++)
                t1[((size_t)(r0 + rg) << 11) + e] = f2bf(acc[mt][nt][rg]);
        }
}

// ---------------- t1 *= tanh(x @ Wue + bue)  (in place) ----------------
__global__ __launch_bounds__(256) void k_u(const u16* __restrict__ xb, const u16* __restrict__ WueT,
                                           const float* __restrict__ bue, u16* __restrict__ t1) {
    const int lane = threadIdx.x & 63, wid = threadIdx.x >> 6;
    const int ln = lane & 15, lh = lane >> 4;
    const int wm = wid >> 1, wn = wid & 1;
    const int mbase = blockIdx.x * 128 + wm * 64;
    const int nbase = blockIdx.y * 128 + wn * 64;
    f4 acc[4][4] = {};
    const u16* ar[4];
    #pragma unroll
    for (int mt = 0; mt < 4; mt++) {
        int r = mbase + mt * 16 + ln;
        ar[mt] = xb + ((size_t)((r & 4095) * 8 + (r >> 12)) << 10);
    }
    const u16* br[4];
    #pragma unroll
    for (int nt = 0; nt < 4; nt++) br[nt] = WueT + ((size_t)(nbase + nt * 16 + ln) << 10);
    for (int kk = 0; kk < 1024; kk += 32) {
        int k0 = kk + lh * 8;
        bf8 a[4], b[4];
        #pragma unroll
        for (int mt = 0; mt < 4; mt++) a[mt] = *reinterpret_cast<const bf8*>(ar[mt] + k0);
        #pragma unroll
        for (int nt = 0; nt < 4; nt++) b[nt] = *reinterpret_cast<const bf8*>(br[nt] + k0);
        #pragma unroll
        for (int mt = 0; mt < 4; mt++)
            #pragma unroll
            for (int nt = 0; nt < 4; nt++)
                acc[mt][nt] = MFMA(a[mt], b[nt], acc[mt][nt]);
    }
    #pragma unroll
    for (int mt = 0; mt < 4; mt++)
        #pragma unroll
        for (int nt = 0; nt < 4; nt++) {
            int e = nbase + nt * 16 + ln;
            float bias = bue[e];
            int r0 = mbase + mt * 16 + lh * 4;
            #pragma unroll
            for (int rg = 0; rg < 4; rg++) {
                size_t idx = ((size_t)(r0 + rg) << 11) + e;
                float t = bf2f(t1[idx]);
                float u = tanhf_fast(acc[mt][nt][rg] + bias);
                t1[idx] = f2bf(u * t);
            }
        }
}

// ---------------- out = t1 @ Wod + bod -> [s][b][d] f32 ----------------
__global__ __launch_bounds__(256) void k_o(const u16* __restrict__ t1, const u16* __restrict__ WodT,
                                           const float* __restrict__ bod, float* __restrict__ out) {
    const int lane = threadIdx.x & 63, wid = threadIdx.x >> 6;
    const int ln = lane & 15, lh = lane >> 4;
    const int wm = wid >> 1, wn = wid & 1;
    const int mbase = blockIdx.x * 128 + wm * 64;
    const int nbase = blockIdx.y * 128 + wn * 64;
    f4 acc[4][4] = {};
    const u16* ar[4];
    #pragma unroll
    for (int mt = 0; mt < 4; mt++) ar[mt] = t1 + ((size_t)(mbase + mt * 16 + ln) << 11);
    const u16* br[4];
    #pragma unroll
    for (int nt = 0; nt < 4; nt++) br[nt] = WodT + ((size_t)(nbase + nt * 16 + ln) << 11);
    for (int kk = 0; kk < 2048; kk += 32) {
        int k0 = kk + lh * 8;
        bf8 a[4], b[4];
        #pragma unroll
        for (int mt = 0; mt < 4; mt++) a[mt] = *reinterpret_cast<const bf8*>(ar[mt] + k0);
        #pragma unroll
        for (int nt = 0; nt < 4; nt++) b[nt] = *reinterpret_cast<const bf8*>(br[nt] + k0);
        #pragma unroll
        for (int mt = 0; mt < 4; mt++)
            #pragma unroll
            for (int nt = 0; nt < 4; nt++)
                acc[mt][nt] = MFMA(a[mt], b[nt], acc[mt][nt]);
    }
    #pragma unroll
    for (int mt = 0; mt < 4; mt++)
        #pragma unroll
        for (int nt = 0; nt < 4; nt++) {
            int d = nbase + nt * 16 + ln;
            float bias = bod[d];
            int r0 = mbase + mt * 16 + lh * 4;
            #pragma unroll
            for (int rg = 0; rg < 4; rg++) {
                int r = r0 + rg;
                int s = r & 4095, bb = r >> 12;
                out[((size_t)(s * 8 + bb) << 10) + d] = acc[mt][nt][rg] + bias;
            }
        }
}

extern "C" void kernel_launch(void* const* d_in, const int* in_sizes, int n_in,
                              void* d_out, int out_size, void* d_ws, size_t ws_size,
                              hipStream_t stream) {
    const float* value = (const float*)d_in[2];
    const float* Wxs = (const float*)d_in[3];  const float* bxs = (const float*)d_in[4];
    const float* Wve = (const float*)d_in[5];  const float* bve = (const float*)d_in[6];
    const float* Wue = (const float*)d_in[7];  const float* bue = (const float*)d_in[8];
    const float* Wod = (const float*)d_in[9];  const float* bod = (const float*)d_in[10];
    const float* rel_bias = (const float*)d_in[11];
    const float* gamma = (const float*)d_in[12];
    const float* beta  = (const float*)d_in[13];
    float* out = (float*)d_out;

    char* ws = (char*)d_ws;
    u16* xb   = (u16*)(ws + WS_XB);
    u16* WxsT = (u16*)(ws + WS_WXST);
    u16* WveT = (u16*)(ws + WS_WVET);
    u16* WueT = (u16*)(ws + WS_WUET);
    u16* WodT = (u16*)(ws + WS_WODT);
    u16* z    = (u16*)(ws + WS_Z);
    u16* vT   = (u16*)(ws + WS_VT);
    u16* kvT  = (u16*)(ws + WS_KVT);
    u16* a    = (u16*)(ws + WS_A);
    u16* t1   = (u16*)(ws + WS_T1);
    float* kvF = (float*)(ws + WS_KVF);

    // conversions
    k_cvt_x<<<32768, 256, 0, stream>>>(value, xb, 33554432);
    k_transpose<<<dim3(4, 32),  256, 0, stream>>>(Wxs, WxsT, 1024, 128);
    k_transpose<<<dim3(64, 32), 256, 0, stream>>>(Wve, WveT, 1024, 2048);
    k_transpose<<<dim3(64, 32), 256, 0, stream>>>(Wue, WueT, 1024, 2048);
    k_transpose<<<dim3(32, 64), 256, 0, stream>>>(Wod, WodT, 2048, 1024);
    // z, v
    k_zgemm<<<256, 256, 0, stream>>>(xb, WxsT, bxs, z);
    k_vgemm<<<dim3(256, 16), 256, 0, stream>>>(xb, WveT, bve, vT);
    // kv (global linear attention state)
    hipMemsetAsync(kvF, 0, (size_t)8 * 2048 * 128 * 4, stream);
    k_kv<<<dim3(16, 8, 4), 256, 0, stream>>>(vT, z, gamma, beta, kvF);
    k_kvcvt<<<2048, 256, 0, stream>>>(kvF, kvT, 8 * 2048 * 128);
    // quadratic attention scores
    k_a<<<dim3(2, 128), 256, 0, stream>>>(z, gamma, beta, rel_bias, a);
    // t1 = v_quad + v_lin
    k_t1<<<dim3(16, 128), 256, 0, stream>>>(z, a, vT, kvT, gamma, beta, t1);
    // t1 *= u
    k_u<<<dim3(256, 16), 256, 0, stream>>>(xb, WueT, bue, t1);
    // out
    k_o<<<dim3(256, 8), 256, 0, stream>>>(t1, WodT, bod, out);
}

// Round 2
// 1363.740 us; speedup vs baseline: 1.4360x; 1.4360x over previous
//
#include <hip/hip_runtime.h>
#include <hip/hip_bf16.h>

using u16 = unsigned short;
using u32 = unsigned int;

typedef __attribute__((ext_vector_type(8))) short bf8;   // 8 x bf16 bits (4 VGPR)
typedef __attribute__((ext_vector_type(4))) float f4;    // MFMA acc
typedef __attribute__((ext_vector_type(4))) u16  us4;

#define DEV static __device__ __forceinline__

DEV float bf2f(u16 u) { return __uint_as_float(((u32)u) << 16); }
DEV u16 f2bf(float f) {
    u32 x = __float_as_uint(f);
    x += 0x7FFFu + ((x >> 16) & 1u);          // RNE
    return (u16)(x >> 16);
}
DEV float tanhf_fast(float x) {               // tanh = 1 - 2/(e^{2x}+1)
    float e = __expf(2.0f * x);
    return 1.0f - 2.0f / (e + 1.0f);
}
DEV f4 MFMA(bf8 a, bf8 b, f4 c) {
    return __builtin_amdgcn_mfma_f32_16x16x32_bf16(a, b, c, 0, 0, 0);
}

// ---------------- constants ----------------
// D=1024 E=2048 S_DIM=128 C=256 SRC=4096 G=16 B=8, M = B*SRC = 32768 rows
// GEMM row order r = b*4096 + s  (s = g*256 + c); xb stored r-major [r][1024]

// ---------------- workspace layout (bytes) ----------------
#define WS_XB    ((size_t)0)                    // bf16 x, [r][1024] r-major              64 MiB
#define WS_WXST  ((size_t)67108864)             // WxsT [128][1024]                       256 KiB
#define WS_WVET  ((size_t)67371008)             // WveT [2048][1024]                      4 MiB
#define WS_WUET  ((size_t)71565312)             // WueT [2048][1024]                      4 MiB
#define WS_WODT  ((size_t)75759616)             // WodT [1024][2048]                      4 MiB
#define WS_Z     ((size_t)79953920)             // z bf16 [32768][128]                    8 MiB
#define WS_VT    ((size_t)88342528)             // vT bf16 [B][2048][4096]                128 MiB
#define WS_KVT   ((size_t)222560256)            // kvT bf16 [B][2048][128]                4 MiB
#define WS_A     ((size_t)226754560)            // a bf16 [128][256][256]                 16 MiB
#define WS_T1    ((size_t)243531776)            // t1 bf16 [32768][2048]                  128 MiB
#define WS_KLT   ((size_t)377749504)            // klinT bf16 [B][128][4096]              8 MiB
// total 386,138,112 bytes

// ================= staged-GEMM building blocks (m97 structure) =================
// tile 128x128, BK=64, 4 waves, wave (wm,wn) computes 64x64.
// LDS: As[128][64], Bs[128][64] bf16 (16 KiB each)

DEV void stage128x64(const u16* __restrict__ gbase, int ld, u16* lds, int w, int lane) {
    // stages a [128 rows][64 cols] bf16 tile starting at gbase (row-major, stride ld)
    const int srow = lane >> 3;             // 0..7
    const int scol = (lane & 7) * 8;        // 0,8,..56
    #pragma unroll
    for (int i = 0; i < 4; i++) {
        const int rt = (i * 4 + w) * 8 + srow;
        const u16* src = gbase + (size_t)rt * ld + scol;
        u16* dst = lds + (size_t)(i * 4 + w) * 512;   // wave-uniform base; HW adds lane*16B
        __builtin_amdgcn_global_load_lds(
            (const __attribute__((address_space(1))) void*)src,
            (__attribute__((address_space(3))) void*)dst, 16, 0, 0);
    }
}

DEV void frag_mfma_64(const u16* As, const u16* Bs, int wm, int wn, int ln, int lh,
                      f4 acc[4][4]) {
    #pragma unroll
    for (int kk = 0; kk < 64; kk += 32) {
        bf8 a[4], b[4];
        #pragma unroll
        for (int mt = 0; mt < 4; mt++)
            a[mt] = *reinterpret_cast<const bf8*>(As + (wm * 64 + mt * 16 + ln) * 64 + kk + lh * 8);
        #pragma unroll
        for (int nt = 0; nt < 4; nt++)
            b[nt] = *reinterpret_cast<const bf8*>(Bs + (wn * 64 + nt * 16 + ln) * 64 + kk + lh * 8);
        #pragma unroll
        for (int mt = 0; mt < 4; mt++)
            #pragma unroll
            for (int nt = 0; nt < 4; nt++)
                acc[mt][nt] = MFMA(a[mt], b[nt], acc[mt][nt]);
    }
}

// ---------------- conversion kernels ----------------
// value [s][b][d] f32 -> xb [b*4096+s][d] bf16
__global__ void k_cvt_x(const float* __restrict__ src, u16* __restrict__ dst) {
    int m = blockIdx.x;                 // m = s*8 + b
    int s = m >> 3, b = m & 7;
    const float* in = src + (size_t)m * 1024;
    u16* outp = dst + (((size_t)b << 12) + s) * 1024;
    int t = threadIdx.x * 4;
    float4 v = *reinterpret_cast<const float4*>(in + t);
    us4 o; o[0] = f2bf(v.x); o[1] = f2bf(v.y); o[2] = f2bf(v.z); o[3] = f2bf(v.w);
    *reinterpret_cast<us4*>(outp + t) = o;
}

// src[R][C] f32 -> dst[C][R] bf16
__global__ void k_transpose(const float* __restrict__ src, u16* __restrict__ dst, int R, int C) {
    __shared__ u16 tile[32][33];
    int tx = threadIdx.x & 31, ty = threadIdx.x >> 5;   // 256 thr: 32x8
    int r0 = blockIdx.y * 32, c0 = blockIdx.x * 32;
    #pragma unroll
    for (int rr = ty; rr < 32; rr += 8)
        tile[rr][tx] = f2bf(src[(size_t)(r0 + rr) * C + c0 + tx]);
    __syncthreads();
    #pragma unroll
    for (int cc = ty; cc < 32; cc += 8)
        dst[(size_t)(c0 + cc) * R + r0 + tx] = tile[tx][cc];
}

// z rows -> klinT[b][s][pos] with affine (gamma3,beta3)
__global__ void k_klinT(const u16* __restrict__ z, const float* __restrict__ gamma,
                        const float* __restrict__ beta, u16* __restrict__ klt) {
    __shared__ u16 tile[32][33];
    int tx = threadIdx.x & 31, ty = threadIdx.x >> 5;
    int r0 = blockIdx.x * 32;            // global row (0..32767)
    int c0 = blockIdx.y * 32;            // s col (0..127)
    float gs = gamma[384 + c0 + tx], bs = beta[384 + c0 + tx];
    #pragma unroll
    for (int rr = ty; rr < 32; rr += 8) {
        u16 zv = z[(size_t)(r0 + rr) * 128 + c0 + tx];
        tile[rr][tx] = f2bf(bf2f(zv) * gs + bs);
    }
    __syncthreads();
    int b = r0 >> 12;
    int pos0 = r0 & 4095;
    #pragma unroll
    for (int cc = ty; cc < 32; cc += 8)
        klt[(((size_t)b * 128 + c0 + cc) << 12) + pos0 + tx] = tile[tx][cc];
}

// ---------------- z = tanh(x @ Wxs + bxs), bf16 [32768][128] ----------------
__global__ __launch_bounds__(256) void k_zgemm(const u16* __restrict__ xb, const u16* __restrict__ WxsT,
                                               const float* __restrict__ bxs, u16* __restrict__ z) {
    const int lane = threadIdx.x & 63, wid = threadIdx.x >> 6;
    const int ln = lane & 15, lh = lane >> 4;
    const int mbase = blockIdx.x * 128 + wid * 32;      // wave: 32 rows x 128 cols
    f4 acc[2][8] = {};
    const u16* ar[2];
    #pragma unroll
    for (int mt = 0; mt < 2; mt++)
        ar[mt] = xb + ((size_t)(mbase + mt * 16 + ln) << 10);
    const u16* br[8];
    #pragma unroll
    for (int nt = 0; nt < 8; nt++) br[nt] = WxsT + ((size_t)(nt * 16 + ln) << 10);
    for (int kk = 0; kk < 1024; kk += 32) {
        int k0 = kk + lh * 8;
        bf8 a[2], b[8];
        #pragma unroll
        for (int mt = 0; mt < 2; mt++) a[mt] = *reinterpret_cast<const bf8*>(ar[mt] + k0);
        #pragma unroll
        for (int nt = 0; nt < 8; nt++) b[nt] = *reinterpret_cast<const bf8*>(br[nt] + k0);
        #pragma unroll
        for (int mt = 0; mt < 2; mt++)
            #pragma unroll
            for (int nt = 0; nt < 8; nt++)
                acc[mt][nt] = MFMA(a[mt], b[nt], acc[mt][nt]);
    }
    #pragma unroll
    for (int mt = 0; mt < 2; mt++)
        #pragma unroll
        for (int nt = 0; nt < 8; nt++) {
            int col = nt * 16 + ln;
            float bias = bxs[col];
            int r0 = mbase + mt * 16 + lh * 4;
            #pragma unroll
            for (int rg = 0; rg < 4; rg++)
                z[((size_t)(r0 + rg) << 7) + col] = f2bf(tanhf_fast(acc[mt][nt][rg] + bias));
        }
}

// ---------------- vT = tanh(x @ Wve + bve)^T : bf16 [B][2048][4096] (staged) ----------------
__global__ __launch_bounds__(256) void k_vgemm(const u16* __restrict__ xb, const u16* __restrict__ WveT,
                                               const float* __restrict__ bve, u16* __restrict__ vT) {
    __shared__ u16 As[128 * 64];
    __shared__ u16 Bs[128 * 64];
    const int tid = threadIdx.x;
    const int lane = tid & 63, w = tid >> 6;
    const int ln = lane & 15, lh = lane >> 4;
    const int wm = w >> 1, wn = w & 1;
    const int rowbase = blockIdx.x * 128;
    const int colbase = blockIdx.y * 128;
    f4 acc[4][4] = {};
    for (int kt = 0; kt < 1024; kt += 64) {
        stage128x64(xb + (size_t)rowbase * 1024 + kt, 1024, As, w, lane);
        stage128x64(WveT + (size_t)colbase * 1024 + kt, 1024, Bs, w, lane);
        __syncthreads();
        frag_mfma_64(As, Bs, wm, wn, ln, lh, acc);
        __syncthreads();
    }
    #pragma unroll
    for (int mt = 0; mt < 4; mt++)
        #pragma unroll
        for (int nt = 0; nt < 4; nt++) {
            int e = colbase + wn * 64 + nt * 16 + ln;
            float bias = bve[e];
            int r0 = rowbase + wm * 64 + mt * 16 + lh * 4;
            int bb = r0 >> 12, s0 = r0 & 4095;       // 4 consecutive s, same b
            us4 p;
            #pragma unroll
            for (int rg = 0; rg < 4; rg++) p[rg] = f2bf(tanhf_fast(acc[mt][nt][rg] + bias));
            *reinterpret_cast<us4*>(vT + (((size_t)bb * 2048 + e) << 12) + s0) = p;
        }
}

// ---------------- kvT[b][e][s] = sum_pos vT[b][e][pos] * klinT[b][s][pos] (staged GEMM) ----------------
__global__ __launch_bounds__(256) void k_kv(const u16* __restrict__ vT, const u16* __restrict__ klt,
                                            u16* __restrict__ kvT) {
    __shared__ u16 As[128 * 64];
    __shared__ u16 Bs[128 * 64];
    const int tid = threadIdx.x;
    const int lane = tid & 63, w = tid >> 6;
    const int ln = lane & 15, lh = lane >> 4;
    const int wm = w >> 1, wn = w & 1;
    const int b = blockIdx.z;
    const int rowbase = blockIdx.x * 128;            // e
    const u16* A = vT + ((size_t)b * 2048) * 4096;
    const u16* B = klt + ((size_t)b * 128) * 4096;
    f4 acc[4][4] = {};
    for (int kt = 0; kt < 4096; kt += 64) {
        stage128x64(A + (size_t)rowbase * 4096 + kt, 4096, As, w, lane);
        stage128x64(B + kt, 4096, Bs, w, lane);
        __syncthreads();
        frag_mfma_64(As, Bs, wm, wn, ln, lh, acc);
        __syncthreads();
    }
    #pragma unroll
    for (int mt = 0; mt < 4; mt++)
        #pragma unroll
        for (int nt = 0; nt < 4; nt++) {
            int s = wn * 64 + nt * 16 + ln;
            int e0 = rowbase + wm * 64 + mt * 16 + lh * 4;
            #pragma unroll
            for (int rg = 0; rg < 4; rg++)
                kvT[(((size_t)b * 2048 + e0 + rg) << 7) + s] = f2bf(acc[mt][nt][rg]);
        }
}

// ---------------- a = relu(q_quad @ k_quad^T + rel_bias)^2 : bf16 [128][256][256] ----------------
__global__ __launch_bounds__(256) void k_a(const u16* __restrict__ z, const float* __restrict__ gamma,
                                           const float* __restrict__ beta, const float* __restrict__ rel_bias,
                                           u16* __restrict__ a_out) {
    const int lane = threadIdx.x & 63, wid = threadIdx.x >> 6;
    const int ln = lane & 15, lh = lane >> 4;
    const int wm = wid >> 1, wn = wid & 1;
    const int ci = blockIdx.y;
    const int qbase = blockIdx.x * 128 + wm * 64;    // q rows within chunk
    const int nbase = wn * 128;                      // key cols within chunk
    const int rowbase = ci << 8;
    const float* g0 = gamma,       *b0 = beta;
    const float* g1 = gamma + 128, *b1 = beta + 128;
    f4 acc[4][8] = {};
    const u16* qr[4];
    #pragma unroll
    for (int mt = 0; mt < 4; mt++) qr[mt] = z + ((size_t)(rowbase + qbase + mt * 16 + ln) << 7);
    const u16* kr[8];
    #pragma unroll
    for (int nt = 0; nt < 8; nt++) kr[nt] = z + ((size_t)(rowbase + nbase + nt * 16 + ln) << 7);
    for (int kk = 0; kk < 128; kk += 32) {
        int k0 = kk + lh * 8;
        float gq[8], bq[8], gk[8], bk[8];
        #pragma unroll
        for (int j = 0; j < 8; j++) { gq[j] = g0[k0 + j]; bq[j] = b0[k0 + j]; gk[j] = g1[k0 + j]; bk[j] = b1[k0 + j]; }
        bf8 aq[4], ak[8];
        #pragma unroll
        for (int mt = 0; mt < 4; mt++) {
            bf8 zz = *reinterpret_cast<const bf8*>(qr[mt] + k0);
            #pragma unroll
            for (int j = 0; j < 8; j++) aq[mt][j] = (short)f2bf(bf2f((u16)zz[j]) * gq[j] + bq[j]);
        }
        #pragma unroll
        for (int nt = 0; nt < 8; nt++) {
            bf8 zz = *reinterpret_cast<const bf8*>(kr[nt] + k0);
            #pragma unroll
            for (int j = 0; j < 8; j++) ak[nt][j] = (short)f2bf(bf2f((u16)zz[j]) * gk[j] + bk[j]);
        }
        #pragma unroll
        for (int mt = 0; mt < 4; mt++)
            #pragma unroll
            for (int nt = 0; nt < 8; nt++)
                acc[mt][nt] = MFMA(aq[mt], ak[nt], acc[mt][nt]);
    }
    #pragma unroll
    for (int nt = 0; nt < 8; nt++) {
        int key = nbase + nt * 16 + ln;
        float rb = rel_bias[key];
        #pragma unroll
        for (int mt = 0; mt < 4; mt++) {
            int r0 = qbase + mt * 16 + lh * 4;
            #pragma unroll
            for (int rg = 0; rg < 4; rg++) {
                float v = acc[mt][nt][rg] + rb;
                v = fmaxf(v, 0.0f); v = v * v;
                a_out[((size_t)ci << 16) + ((size_t)(r0 + rg) << 8) + key] = f2bf(v);
            }
        }
    }
}

// ---------------- t1 = tanh(x@Wue+bue) * (q_lin @ kv + a @ v) : bf16 [32768][2048] ----------------
__global__ __launch_bounds__(256) void k_t1u(const u16* __restrict__ z, const u16* __restrict__ a_in,
                                             const u16* __restrict__ vT, const u16* __restrict__ kvT,
                                             const u16* __restrict__ xb, const u16* __restrict__ WueT,
                                             const float* __restrict__ gamma, const float* __restrict__ beta,
                                             const float* __restrict__ bue, u16* __restrict__ t1) {
    __shared__ u16 As[128 * 64];
    __shared__ u16 Bs[128 * 64];
    const int tid = threadIdx.x;
    const int lane = tid & 63, w = tid >> 6;
    const int ln = lane & 15, lh = lane >> 4;
    const int wm = w >> 1, wn = w & 1;
    const int bx = blockIdx.x;
    const int rowbase = bx * 128;
    const int ebase0 = blockIdx.y * 128;
    const int ci = bx >> 1;
    const int b = ci >> 4, g = ci & 15;
    f4 acc_t[4][4] = {};
    f4 acc_u[4][4] = {};

    // phase c (staged): acc_u = x @ Wue  (K = 1024)
    for (int kt = 0; kt < 1024; kt += 64) {
        stage128x64(xb + (size_t)rowbase * 1024 + kt, 1024, As, w, lane);
        stage128x64(WueT + (size_t)ebase0 * 1024 + kt, 1024, Bs, w, lane);
        __syncthreads();
        frag_mfma_64(As, Bs, wm, wn, ln, lh, acc_u);
        __syncthreads();
    }

    // phase a: acc_t += q_lin @ kv^T   (K = 128 s)
    {
        const float* g2 = gamma + 256, *b2 = beta + 256;
        const u16* qr[4];
        #pragma unroll
        for (int mt = 0; mt < 4; mt++)
            qr[mt] = z + ((size_t)(rowbase + wm * 64 + mt * 16 + ln) << 7);
        const u16* kvr[4];
        #pragma unroll
        for (int nt = 0; nt < 4; nt++)
            kvr[nt] = kvT + ((size_t)(b * 2048 + ebase0 + wn * 64 + nt * 16 + ln) << 7);
        #pragma unroll
        for (int kk = 0; kk < 128; kk += 32) {
            int k0 = kk + lh * 8;
            float gq[8], bq[8];
            #pragma unroll
            for (int j = 0; j < 8; j++) { gq[j] = g2[k0 + j]; bq[j] = b2[k0 + j]; }
            bf8 aq[4], bv[4];
            #pragma unroll
            for (int mt = 0; mt < 4; mt++) {
                bf8 zz = *reinterpret_cast<const bf8*>(qr[mt] + k0);
                #pragma unroll
                for (int j = 0; j < 8; j++) aq[mt][j] = (short)f2bf(bf2f((u16)zz[j]) * gq[j] + bq[j]);
            }
            #pragma unroll
            for (int nt = 0; nt < 4; nt++) bv[nt] = *reinterpret_cast<const bf8*>(kvr[nt] + k0);
            #pragma unroll
            for (int mt = 0; mt < 4; mt++)
                #pragma unroll
                for (int nt = 0; nt < 4; nt++)
                    acc_t[mt][nt] = MFMA(aq[mt], bv[nt], acc_t[mt][nt]);
        }
    }
    // phase b: acc_t += a @ v   (K = 256 keys)
    {
        const int lqbase = (bx & 1) * 128 + wm * 64;
        const u16* arow[4];
        #pragma unroll
        for (int mt = 0; mt < 4; mt++)
            arow[mt] = a_in + ((size_t)ci << 16) + ((size_t)(lqbase + mt * 16 + ln) << 8);
        const u16* vr[4];
        #pragma unroll
        for (int nt = 0; nt < 4; nt++)
            vr[nt] = vT + (((size_t)b * 2048 + ebase0 + wn * 64 + nt * 16 + ln) << 12) + (g << 8);
        #pragma unroll
        for (int kk = 0; kk < 256; kk += 32) {
            int k0 = kk + lh * 8;
            bf8 aa[4], bb[4];
            #pragma unroll
            for (int mt = 0; mt < 4; mt++) aa[mt] = *reinterpret_cast<const bf8*>(arow[mt] + k0);
            #pragma unroll
            for (int nt = 0; nt < 4; nt++) bb[nt] = *reinterpret_cast<const bf8*>(vr[nt] + k0);
            #pragma unroll
            for (int mt = 0; mt < 4; mt++)
                #pragma unroll
                for (int nt = 0; nt < 4; nt++)
                    acc_t[mt][nt] = MFMA(aa[mt], bb[nt], acc_t[mt][nt]);
        }
    }
    // epilogue: t1 = tanh(acc_u + bue) * acc_t
    #pragma unroll
    for (int mt = 0; mt < 4; mt++)
        #pragma unroll
        for (int nt = 0; nt < 4; nt++) {
            int e = ebase0 + wn * 64 + nt * 16 + ln;
            float bias = bue[e];
            int r0 = rowbase + wm * 64 + mt * 16 + lh * 4;
            #pragma unroll
            for (int rg = 0; rg < 4; rg++) {
                float u = tanhf_fast(acc_u[mt][nt][rg] + bias);
                t1[((size_t)(r0 + rg) << 11) + e] = f2bf(u * acc_t[mt][nt][rg]);
            }
        }
}

// ---------------- out = t1 @ Wod + bod -> [s][b][d] f32 (staged) ----------------
__global__ __launch_bounds__(256) void k_o(const u16* __restrict__ t1, const u16* __restrict__ WodT,
                                           const float* __restrict__ bod, float* __restrict__ out) {
    __shared__ u16 As[128 * 64];
    __shared__ u16 Bs[128 * 64];
    const int tid = threadIdx.x;
    const int lane = tid & 63, w = tid >> 6;
    const int ln = lane & 15, lh = lane >> 4;
    const int wm = w >> 1, wn = w & 1;
    const int rowbase = blockIdx.x * 128;
    const int colbase = blockIdx.y * 128;
    f4 acc[4][4] = {};
    for (int kt = 0; kt < 2048; kt += 64) {
        stage128x64(t1 + (size_t)rowbase * 2048 + kt, 2048, As, w, lane);
        stage128x64(WodT + (size_t)colbase * 2048 + kt, 2048, Bs, w, lane);
        __syncthreads();
        frag_mfma_64(As, Bs, wm, wn, ln, lh, acc);
        __syncthreads();
    }
    #pragma unroll
    for (int mt = 0; mt < 4; mt++)
        #pragma unroll
        for (int nt = 0; nt < 4; nt++) {
            int d = colbase + wn * 64 + nt * 16 + ln;
            float bias = bod[d];
            int r0 = rowbase + wm * 64 + mt * 16 + lh * 4;
            #pragma unroll
            for (int rg = 0; rg < 4; rg++) {
                int r = r0 + rg;
                int s = r & 4095, bb = r >> 12;
                out[((size_t)(s * 8 + bb) << 10) + d] = acc[mt][nt][rg] + bias;
            }
        }
}

extern "C" void kernel_launch(void* const* d_in, const int* in_sizes, int n_in,
                              void* d_out, int out_size, void* d_ws, size_t ws_size,
                              hipStream_t stream) {
    const float* value = (const float*)d_in[2];
    const float* Wxs = (const float*)d_in[3];  const float* bxs = (const float*)d_in[4];
    const float* Wve = (const float*)d_in[5];  const float* bve = (const float*)d_in[6];
    const float* Wue = (const float*)d_in[7];  const float* bue = (const float*)d_in[8];
    const float* Wod = (const float*)d_in[9];  const float* bod = (const float*)d_in[10];
    const float* rel_bias = (const float*)d_in[11];
    const float* gamma = (const float*)d_in[12];
    const float* beta  = (const float*)d_in[13];
    float* out = (float*)d_out;

    char* ws = (char*)d_ws;
    u16* xb   = (u16*)(ws + WS_XB);
    u16* WxsT = (u16*)(ws + WS_WXST);
    u16* WveT = (u16*)(ws + WS_WVET);
    u16* WueT = (u16*)(ws + WS_WUET);
    u16* WodT = (u16*)(ws + WS_WODT);
    u16* z    = (u16*)(ws + WS_Z);
    u16* vT   = (u16*)(ws + WS_VT);
    u16* kvT  = (u16*)(ws + WS_KVT);
    u16* a    = (u16*)(ws + WS_A);
    u16* t1   = (u16*)(ws + WS_T1);
    u16* klt  = (u16*)(ws + WS_KLT);

    // conversions
    k_cvt_x<<<32768, 256, 0, stream>>>(value, xb);
    k_transpose<<<dim3(4, 32),  256, 0, stream>>>(Wxs, WxsT, 1024, 128);
    k_transpose<<<dim3(64, 32), 256, 0, stream>>>(Wve, WveT, 1024, 2048);
    k_transpose<<<dim3(64, 32), 256, 0, stream>>>(Wue, WueT, 1024, 2048);
    k_transpose<<<dim3(32, 64), 256, 0, stream>>>(Wod, WodT, 2048, 1024);
    // z
    k_zgemm<<<256, 256, 0, stream>>>(xb, WxsT, bxs, z);
    // k_lin transposed
    k_klinT<<<dim3(1024, 4), 256, 0, stream>>>(z, gamma, beta, klt);
    // v (staged)
    k_vgemm<<<dim3(256, 16), 256, 0, stream>>>(xb, WveT, bve, vT);
    // kv (staged GEMM, no atomics)
    k_kv<<<dim3(16, 1, 8), 256, 0, stream>>>(vT, klt, kvT);
    // quadratic attention scores
    k_a<<<dim3(2, 128), 256, 0, stream>>>(z, gamma, beta, rel_bias, a);
    // t1 = tanh(u) * (v_quad + v_lin)   (u-GEMM fused, staged)
    k_t1u<<<dim3(256, 16), 256, 0, stream>>>(z, a, vT, kvT, xb, WueT, gamma, beta, bue, t1);
    // out (staged)
    k_o<<<dim3(256, 8), 256, 0, stream>>>(t1, WodT, bod, out);
}

// Round 3
// 1356.281 us; speedup vs baseline: 1.4439x; 1.0055x over previous
//
#include <hip/hip_runtime.h>
#include <hip/hip_bf16.h>

using u16 = unsigned short;
using u32 = unsigned int;

typedef __attribute__((ext_vector_type(8))) short bf8;   // 8 x bf16 bits (4 VGPR)
typedef __attribute__((ext_vector_type(4))) float f4;    // MFMA acc
typedef __attribute__((ext_vector_type(4))) u16  us4;

#define DEV static __device__ __forceinline__

DEV float bf2f(u16 u) { return __uint_as_float(((u32)u) << 16); }
DEV u16 f2bf(float f) {
    u32 x = __float_as_uint(f);
    x += 0x7FFFu + ((x >> 16) & 1u);          // RNE
    return (u16)(x >> 16);
}
DEV float tanhf_fast(float x) {               // tanh = 1 - 2/(e^{2x}+1)
    float e = __expf(2.0f * x);
    return 1.0f - 2.0f / (e + 1.0f);
}
DEV f4 MFMA(bf8 a, bf8 b, f4 c) {
    return __builtin_amdgcn_mfma_f32_16x16x32_bf16(a, b, c, 0, 0, 0);
}

// ---------------- constants ----------------
// D=1024 E=2048 S_DIM=128 C=256 SRC=4096 G=16 B=8, M = B*SRC = 32768 rows
// GEMM row order r = b*4096 + s; xb stored r-major [r][1024]

// ---------------- workspace layout (bytes) ----------------
#define WS_XB    ((size_t)0)                    // bf16 x, [r][1024]                      64 MiB
#define WS_WXST  ((size_t)67108864)             // WxsT [128][1024]                       256 KiB
#define WS_WVET  ((size_t)67371008)             // WveT [2048][1024]                      4 MiB
#define WS_WUET  ((size_t)71565312)             // WueT [2048][1024]                      4 MiB
#define WS_WODT  ((size_t)75759616)             // WodT [1024][2048]                      4 MiB
#define WS_KVT   ((size_t)79953920)             // kvT bf16 [B][2048][128]                4 MiB
#define WS_A     ((size_t)84148224)             // a bf16 [128][256][256]                 16 MiB
#define WS_QL    ((size_t)100925440)            // ql bf16 [32768][128] (live in k_t1u)   8 MiB
#define WS_VT    ((size_t)109314048)            // vT bf16 [B][2048][4096]                128 MiB
#define WS_T1    ((size_t)243531776)            // t1 bf16 [32768][2048]                  128 MiB
// --- aliases inside the t1 block: all dead before k_t1u writes t1 ---
#define WS_Z     ((size_t)243531776)            // z bf16 [32768][128]   (dead after k_klinT)  8 MiB
#define WS_KLT   ((size_t)251920384)            // klinT bf16 [B][128][4096] (dead after k_kv) 8 MiB
#define WS_QQ    ((size_t)260308992)            // qq bf16 [32768][128]  (dead after k_a)      8 MiB
#define WS_KQ    ((size_t)268697600)            // kq bf16 [32768][128]  (dead after k_a)      8 MiB
#define WS_KVF   ((size_t)277086208)            // kvF f32 [B][2048][128] (dead after k_kvcvt) 8 MiB
// total 377,749,504 bytes

// ================= staged-GEMM building blocks (m97 structure) =================
DEV void stage128x64(const u16* __restrict__ gbase, int ld, u16* lds, int w, int lane) {
    const int srow = lane >> 3;             // 0..7
    const int scol = (lane & 7) * 8;        // 0,8,..56
    #pragma unroll
    for (int i = 0; i < 4; i++) {
        const int rt = (i * 4 + w) * 8 + srow;
        const u16* src = gbase + (size_t)rt * ld + scol;
        u16* dst = lds + (size_t)(i * 4 + w) * 512;   // wave-uniform base; HW adds lane*16B
        __builtin_amdgcn_global_load_lds(
            (const __attribute__((address_space(1))) void*)src,
            (__attribute__((address_space(3))) void*)dst, 16, 0, 0);
    }
}

DEV void frag_mfma_64(const u16* As, const u16* Bs, int wm, int wn, int ln, int lh,
                      f4 acc[4][4]) {
    #pragma unroll
    for (int kk = 0; kk < 64; kk += 32) {
        bf8 a[4], b[4];
        #pragma unroll
        for (int mt = 0; mt < 4; mt++)
            a[mt] = *reinterpret_cast<const bf8*>(As + (wm * 64 + mt * 16 + ln) * 64 + kk + lh * 8);
        #pragma unroll
        for (int nt = 0; nt < 4; nt++)
            b[nt] = *reinterpret_cast<const bf8*>(Bs + (wn * 64 + nt * 16 + ln) * 64 + kk + lh * 8);
        #pragma unroll
        for (int mt = 0; mt < 4; mt++)
            #pragma unroll
            for (int nt = 0; nt < 4; nt++)
                acc[mt][nt] = MFMA(a[mt], b[nt], acc[mt][nt]);
    }
}

// ---------------- conversion kernels ----------------
// value [s][b][d] f32 -> xb [b*4096+s][d] bf16
__global__ void k_cvt_x(const float* __restrict__ src, u16* __restrict__ dst) {
    int m = blockIdx.x;                 // m = s*8 + b
    int s = m >> 3, b = m & 7;
    const float* in = src + (size_t)m * 1024;
    u16* outp = dst + (((size_t)b << 12) + s) * 1024;
    int t = threadIdx.x * 4;
    float4 v = *reinterpret_cast<const float4*>(in + t);
    us4 o; o[0] = f2bf(v.x); o[1] = f2bf(v.y); o[2] = f2bf(v.z); o[3] = f2bf(v.w);
    *reinterpret_cast<us4*>(outp + t) = o;
}

// src[R][C] f32 -> dst[C][R] bf16
__global__ void k_transpose(const float* __restrict__ src, u16* __restrict__ dst, int R, int C) {
    __shared__ u16 tile[32][33];
    int tx = threadIdx.x & 31, ty = threadIdx.x >> 5;   // 256 thr: 32x8
    int r0 = blockIdx.y * 32, c0 = blockIdx.x * 32;
    #pragma unroll
    for (int rr = ty; rr < 32; rr += 8)
        tile[rr][tx] = f2bf(src[(size_t)(r0 + rr) * C + c0 + tx]);
    __syncthreads();
    #pragma unroll
    for (int cc = ty; cc < 32; cc += 8)
        dst[(size_t)(c0 + cc) * R + r0 + tx] = tile[tx][cc];
}

// z rows -> klinT[b][s][pos] with affine (gamma3,beta3)
__global__ void k_klinT(const u16* __restrict__ z, const float* __restrict__ gamma,
                        const float* __restrict__ beta, u16* __restrict__ klt) {
    __shared__ u16 tile[32][33];
    int tx = threadIdx.x & 31, ty = threadIdx.x >> 5;
    int r0 = blockIdx.x * 32;            // global row (0..32767)
    int c0 = blockIdx.y * 32;            // s col (0..127)
    float gs = gamma[384 + c0 + tx], bs = beta[384 + c0 + tx];
    #pragma unroll
    for (int rr = ty; rr < 32; rr += 8) {
        u16 zv = z[(size_t)(r0 + rr) * 128 + c0 + tx];
        tile[rr][tx] = f2bf(bf2f(zv) * gs + bs);
    }
    __syncthreads();
    int b = r0 >> 12;
    int pos0 = r0 & 4095;
    #pragma unroll
    for (int cc = ty; cc < 32; cc += 8)
        klt[(((size_t)b * 128 + c0 + cc) << 12) + pos0 + tx] = tile[tx][cc];
}

// ---------------- z/qq/kq/ql = affine(tanh(x @ Wxs + bxs)) ----------------
__global__ __launch_bounds__(256) void k_zgemm(const u16* __restrict__ xb, const u16* __restrict__ WxsT,
                                               const float* __restrict__ bxs,
                                               const float* __restrict__ gamma, const float* __restrict__ beta,
                                               u16* __restrict__ z, u16* __restrict__ qq,
                                               u16* __restrict__ kq, u16* __restrict__ ql) {
    const int lane = threadIdx.x & 63, wid = threadIdx.x >> 6;
    const int ln = lane & 15, lh = lane >> 4;
    const int mbase = blockIdx.x * 128 + wid * 32;      // wave: 32 rows x 128 cols
    f4 acc[2][8] = {};
    const u16* ar[2];
    #pragma unroll
    for (int mt = 0; mt < 2; mt++)
        ar[mt] = xb + ((size_t)(mbase + mt * 16 + ln) << 10);
    const u16* br[8];
    #pragma unroll
    for (int nt = 0; nt < 8; nt++) br[nt] = WxsT + ((size_t)(nt * 16 + ln) << 10);
    for (int kk = 0; kk < 1024; kk += 32) {
        int k0 = kk + lh * 8;
        bf8 a[2], b[8];
        #pragma unroll
        for (int mt = 0; mt < 2; mt++) a[mt] = *reinterpret_cast<const bf8*>(ar[mt] + k0);
        #pragma unroll
        for (int nt = 0; nt < 8; nt++) b[nt] = *reinterpret_cast<const bf8*>(br[nt] + k0);
        #pragma unroll
        for (int mt = 0; mt < 2; mt++)
            #pragma unroll
            for (int nt = 0; nt < 8; nt++)
                acc[mt][nt] = MFMA(a[mt], b[nt], acc[mt][nt]);
    }
    #pragma unroll
    for (int mt = 0; mt < 2; mt++)
        #pragma unroll
        for (int nt = 0; nt < 8; nt++) {
            int col = nt * 16 + ln;
            float bias = bxs[col];
            float g0 = gamma[col],       b0 = beta[col];
            float g1 = gamma[128 + col], b1 = beta[128 + col];
            float g2 = gamma[256 + col], b2 = beta[256 + col];
            int r0 = mbase + mt * 16 + lh * 4;
            #pragma unroll
            for (int rg = 0; rg < 4; rg++) {
                float zv = tanhf_fast(acc[mt][nt][rg] + bias);
                size_t idx = ((size_t)(r0 + rg) << 7) + col;
                z[idx]  = f2bf(zv);
                qq[idx] = f2bf(zv * g0 + b0);
                kq[idx] = f2bf(zv * g1 + b1);
                ql[idx] = f2bf(zv * g2 + b2);
            }
        }
}

// ---------------- vT = tanh(x @ Wve + bve)^T : bf16 [B][2048][4096] (staged) ----------------
__global__ __launch_bounds__(256) void k_vgemm(const u16* __restrict__ xb, const u16* __restrict__ WveT,
                                               const float* __restrict__ bve, u16* __restrict__ vT) {
    __shared__ u16 As[128 * 64];
    __shared__ u16 Bs[128 * 64];
    const int tid = threadIdx.x;
    const int lane = tid & 63, w = tid >> 6;
    const int ln = lane & 15, lh = lane >> 4;
    const int wm = w >> 1, wn = w & 1;
    const int rowbase = blockIdx.x * 128;
    const int colbase = blockIdx.y * 128;
    f4 acc[4][4] = {};
    for (int kt = 0; kt < 1024; kt += 64) {
        stage128x64(xb + (size_t)rowbase * 1024 + kt, 1024, As, w, lane);
        stage128x64(WveT + (size_t)colbase * 1024 + kt, 1024, Bs, w, lane);
        __syncthreads();
        frag_mfma_64(As, Bs, wm, wn, ln, lh, acc);
        __syncthreads();
    }
    #pragma unroll
    for (int mt = 0; mt < 4; mt++)
        #pragma unroll
        for (int nt = 0; nt < 4; nt++) {
            int e = colbase + wn * 64 + nt * 16 + ln;
            float bias = bve[e];
            int r0 = rowbase + wm * 64 + mt * 16 + lh * 4;
            int bb = r0 >> 12, s0 = r0 & 4095;       // 4 consecutive s, same b
            us4 p;
            #pragma unroll
            for (int rg = 0; rg < 4; rg++) p[rg] = f2bf(tanhf_fast(acc[mt][nt][rg] + bias));
            *reinterpret_cast<us4*>(vT + (((size_t)bb * 2048 + e) << 12) + s0) = p;
        }
}

// ---------------- kvF[b][e][s] += vT[b][e][kseg] @ klinT[b][s][kseg] (staged, K-split x4) ----------------
__global__ __launch_bounds__(256) void k_kv(const u16* __restrict__ vT, const u16* __restrict__ klt,
                                            float* __restrict__ kvF) {
    __shared__ u16 As[128 * 64];
    __shared__ u16 Bs[128 * 64];
    const int tid = threadIdx.x;
    const int lane = tid & 63, w = tid >> 6;
    const int ln = lane & 15, lh = lane >> 4;
    const int wm = w >> 1, wn = w & 1;
    const int b = blockIdx.z;
    const int rowbase = blockIdx.x * 128;            // e
    const int kbase = blockIdx.y * 1024;             // pos segment
    const u16* A = vT + ((size_t)b * 2048) * 4096;
    const u16* B = klt + ((size_t)b * 128) * 4096;
    f4 acc[4][4] = {};
    for (int kt = kbase; kt < kbase + 1024; kt += 64) {
        stage128x64(A + (size_t)rowbase * 4096 + kt, 4096, As, w, lane);
        stage128x64(B + kt, 4096, Bs, w, lane);
        __syncthreads();
        frag_mfma_64(As, Bs, wm, wn, ln, lh, acc);
        __syncthreads();
    }
    #pragma unroll
    for (int mt = 0; mt < 4; mt++)
        #pragma unroll
        for (int nt = 0; nt < 4; nt++) {
            int s = wn * 64 + nt * 16 + ln;
            int e0 = rowbase + wm * 64 + mt * 16 + lh * 4;
            #pragma unroll
            for (int rg = 0; rg < 4; rg++)
                atomicAdd(&kvF[(((size_t)b * 2048 + e0 + rg) << 7) + s], acc[mt][nt][rg]);
        }
}

__global__ void k_kvcvt(const float* __restrict__ kvF, u16* __restrict__ kvT, int n) {
    int i = (blockIdx.x * blockDim.x + threadIdx.x) * 4;
    if (i < n) {
        float4 v = *reinterpret_cast<const float4*>(kvF + i);
        us4 o; o[0] = f2bf(v.x); o[1] = f2bf(v.y); o[2] = f2bf(v.z); o[3] = f2bf(v.w);
        *reinterpret_cast<us4*>(kvT + i) = o;
    }
}

// ---------------- a = relu(qq @ kq^T + rel_bias)^2 : bf16 [128][256][256] (pure GEMM) ----------------
__global__ __launch_bounds__(256) void k_a(const u16* __restrict__ qq, const u16* __restrict__ kq,
                                           const float* __restrict__ rel_bias, u16* __restrict__ a_out) {
    const int lane = threadIdx.x & 63, wid = threadIdx.x >> 6;
    const int ln = lane & 15, lh = lane >> 4;
    const int wm = wid >> 1, wn = wid & 1;
    const int ci = blockIdx.y;
    const int qbase = blockIdx.x * 128 + wm * 64;    // q rows within chunk
    const int nbase = wn * 128;                      // key cols within chunk
    const int rowbase = ci << 8;
    f4 acc[4][8] = {};
    const u16* qr[4];
    #pragma unroll
    for (int mt = 0; mt < 4; mt++) qr[mt] = qq + ((size_t)(rowbase + qbase + mt * 16 + ln) << 7);
    const u16* kr[8];
    #pragma unroll
    for (int nt = 0; nt < 8; nt++) kr[nt] = kq + ((size_t)(rowbase + nbase + nt * 16 + ln) << 7);
    #pragma unroll
    for (int kk = 0; kk < 128; kk += 32) {
        int k0 = kk + lh * 8;
        bf8 aq[4], ak[8];
        #pragma unroll
        for (int mt = 0; mt < 4; mt++) aq[mt] = *reinterpret_cast<const bf8*>(qr[mt] + k0);
        #pragma unroll
        for (int nt = 0; nt < 8; nt++) ak[nt] = *reinterpret_cast<const bf8*>(kr[nt] + k0);
        #pragma unroll
        for (int mt = 0; mt < 4; mt++)
            #pragma unroll
            for (int nt = 0; nt < 8; nt++)
                acc[mt][nt] = MFMA(aq[mt], ak[nt], acc[mt][nt]);
    }
    #pragma unroll
    for (int nt = 0; nt < 8; nt++) {
        int key = nbase + nt * 16 + ln;
        float rb = rel_bias[key];
        #pragma unroll
        for (int mt = 0; mt < 4; mt++) {
            int r0 = qbase + mt * 16 + lh * 4;
            #pragma unroll
            for (int rg = 0; rg < 4; rg++) {
                float v = acc[mt][nt][rg] + rb;
                v = fmaxf(v, 0.0f); v = v * v;
                a_out[((size_t)ci << 16) + ((size_t)(r0 + rg) << 8) + key] = f2bf(v);
            }
        }
    }
}

// ---------------- t1 = tanh(x@Wue+bue) * (ql @ kv + a @ v) : bf16 [32768][2048] ----------------
__global__ __launch_bounds__(256) void k_t1u(const u16* __restrict__ ql, const u16* __restrict__ a_in,
                                             const u16* __restrict__ vT, const u16* __restrict__ kvT,
                                             const u16* __restrict__ xb, const u16* __restrict__ WueT,
                                             const float* __restrict__ bue, u16* __restrict__ t1) {
    __shared__ u16 As[128 * 64];
    __shared__ u16 Bs[128 * 64];
    const int tid = threadIdx.x;
    const int lane = tid & 63, w = tid >> 6;
    const int ln = lane & 15, lh = lane >> 4;
    const int wm = w >> 1, wn = w & 1;
    const int bx = blockIdx.x;
    const int rowbase = bx * 128;
    const int ebase0 = blockIdx.y * 128;
    const int ci = bx >> 1;
    const int b = ci >> 4, g = ci & 15;

    // ---- phase c (staged): u = tanh(x @ Wue + bue), packed to bf16 regs ----
    us4 up[4][4];
    {
        f4 acc_u[4][4] = {};
        for (int kt = 0; kt < 1024; kt += 64) {
            stage128x64(xb + (size_t)rowbase * 1024 + kt, 1024, As, w, lane);
            stage128x64(WueT + (size_t)ebase0 * 1024 + kt, 1024, Bs, w, lane);
            __syncthreads();
            frag_mfma_64(As, Bs, wm, wn, ln, lh, acc_u);
            __syncthreads();
        }
        #pragma unroll
        for (int mt = 0; mt < 4; mt++)
            #pragma unroll
            for (int nt = 0; nt < 4; nt++) {
                int e = ebase0 + wn * 64 + nt * 16 + ln;
                float bias = bue[e];
                #pragma unroll
                for (int rg = 0; rg < 4; rg++)
                    up[mt][nt][rg] = f2bf(tanhf_fast(acc_u[mt][nt][rg] + bias));
            }
    }

    f4 acc_t[4][4] = {};
    // ---- phase a: acc_t += ql @ kvT^T   (K = 128 s) ----
    {
        const u16* qr[4];
        #pragma unroll
        for (int mt = 0; mt < 4; mt++)
            qr[mt] = ql + ((size_t)(rowbase + wm * 64 + mt * 16 + ln) << 7);
        const u16* kvr[4];
        #pragma unroll
        for (int nt = 0; nt < 4; nt++)
            kvr[nt] = kvT + ((size_t)(b * 2048 + ebase0 + wn * 64 + nt * 16 + ln) << 7);
        #pragma unroll
        for (int kk = 0; kk < 128; kk += 32) {
            int k0 = kk + lh * 8;
            bf8 aq[4], bv[4];
            #pragma unroll
            for (int mt = 0; mt < 4; mt++) aq[mt] = *reinterpret_cast<const bf8*>(qr[mt] + k0);
            #pragma unroll
            for (int nt = 0; nt < 4; nt++) bv[nt] = *reinterpret_cast<const bf8*>(kvr[nt] + k0);
            #pragma unroll
            for (int mt = 0; mt < 4; mt++)
                #pragma unroll
                for (int nt = 0; nt < 4; nt++)
                    acc_t[mt][nt] = MFMA(aq[mt], bv[nt], acc_t[mt][nt]);
        }
    }
    // ---- phase b: acc_t += a @ v   (K = 256 keys) ----
    {
        const int lqbase = (bx & 1) * 128 + wm * 64;
        const u16* arow[4];
        #pragma unroll
        for (int mt = 0; mt < 4; mt++)
            arow[mt] = a_in + ((size_t)ci << 16) + ((size_t)(lqbase + mt * 16 + ln) << 8);
        const u16* vr[4];
        #pragma unroll
        for (int nt = 0; nt < 4; nt++)
            vr[nt] = vT + (((size_t)b * 2048 + ebase0 + wn * 64 + nt * 16 + ln) << 12) + (g << 8);
        #pragma unroll
        for (int kk = 0; kk < 256; kk += 32) {
            int k0 = kk + lh * 8;
            bf8 aa[4], bb[4];
            #pragma unroll
            for (int mt = 0; mt < 4; mt++) aa[mt] = *reinterpret_cast<const bf8*>(arow[mt] + k0);
            #pragma unroll
            for (int nt = 0; nt < 4; nt++) bb[nt] = *reinterpret_cast<const bf8*>(vr[nt] + k0);
            #pragma unroll
            for (int mt = 0; mt < 4; mt++)
                #pragma unroll
                for (int nt = 0; nt < 4; nt++)
                    acc_t[mt][nt] = MFMA(aa[mt], bb[nt], acc_t[mt][nt]);
        }
    }
    // ---- epilogue: t1 = u * acc_t ----
    #pragma unroll
    for (int mt = 0; mt < 4; mt++)
        #pragma unroll
        for (int nt = 0; nt < 4; nt++) {
            int e = ebase0 + wn * 64 + nt * 16 + ln;
            int r0 = rowbase + wm * 64 + mt * 16 + lh * 4;
            #pragma unroll
            for (int rg = 0; rg < 4; rg++) {
                float u = bf2f(up[mt][nt][rg]);
                t1[((size_t)(r0 + rg) << 11) + e] = f2bf(u * acc_t[mt][nt][rg]);
            }
        }
}

// ---------------- out = t1 @ Wod + bod -> [s][b][d] f32 (staged) ----------------
__global__ __launch_bounds__(256) void k_o(const u16* __restrict__ t1, const u16* __restrict__ WodT,
                                           const float* __restrict__ bod, float* __restrict__ out) {
    __shared__ u16 As[128 * 64];
    __shared__ u16 Bs[128 * 64];
    const int tid = threadIdx.x;
    const int lane = tid & 63, w = tid >> 6;
    const int ln = lane & 15, lh = lane >> 4;
    const int wm = w >> 1, wn = w & 1;
    const int rowbase = blockIdx.x * 128;
    const int colbase = blockIdx.y * 128;
    f4 acc[4][4] = {};
    for (int kt = 0; kt < 2048; kt += 64) {
        stage128x64(t1 + (size_t)rowbase * 2048 + kt, 2048, As, w, lane);
        stage128x64(WodT + (size_t)colbase * 2048 + kt, 2048, Bs, w, lane);
        __syncthreads();
        frag_mfma_64(As, Bs, wm, wn, ln, lh, acc);
        __syncthreads();
    }
    #pragma unroll
    for (int mt = 0; mt < 4; mt++)
        #pragma unroll
        for (int nt = 0; nt < 4; nt++) {
            int d = colbase + wn * 64 + nt * 16 + ln;
            float bias = bod[d];
            int r0 = rowbase + wm * 64 + mt * 16 + lh * 4;
            #pragma unroll
            for (int rg = 0; rg < 4; rg++) {
                int r = r0 + rg;
                int s = r & 4095, bb = r >> 12;
                out[((size_t)(s * 8 + bb) << 10) + d] = acc[mt][nt][rg] + bias;
            }
        }
}

extern "C" void kernel_launch(void* const* d_in, const int* in_sizes, int n_in,
                              void* d_out, int out_size, void* d_ws, size_t ws_size,
                              hipStream_t stream) {
    const float* value = (const float*)d_in[2];
    const float* Wxs = (const float*)d_in[3];  const float* bxs = (const float*)d_in[4];
    const float* Wve = (const float*)d_in[5];  const float* bve = (const float*)d_in[6];
    const float* Wue = (const float*)d_in[7];  const float* bue = (const float*)d_in[8];
    const float* Wod = (const float*)d_in[9];  const float* bod = (const float*)d_in[10];
    const float* rel_bias = (const float*)d_in[11];
    const float* gamma = (const float*)d_in[12];
    const float* beta  = (const float*)d_in[13];
    float* out = (float*)d_out;

    char* ws = (char*)d_ws;
    u16* xb   = (u16*)(ws + WS_XB);
    u16* WxsT = (u16*)(ws + WS_WXST);
    u16* WveT = (u16*)(ws + WS_WVET);
    u16* WueT = (u16*)(ws + WS_WUET);
    u16* WodT = (u16*)(ws + WS_WODT);
    u16* kvT  = (u16*)(ws + WS_KVT);
    u16* a    = (u16*)(ws + WS_A);
    u16* ql   = (u16*)(ws + WS_QL);
    u16* vT   = (u16*)(ws + WS_VT);
    u16* t1   = (u16*)(ws + WS_T1);
    u16* z    = (u16*)(ws + WS_Z);
    u16* klt  = (u16*)(ws + WS_KLT);
    u16* qq   = (u16*)(ws + WS_QQ);
    u16* kq   = (u16*)(ws + WS_KQ);
    float* kvF = (float*)(ws + WS_KVF);

    // conversions
    k_cvt_x<<<32768, 256, 0, stream>>>(value, xb);
    k_transpose<<<dim3(4, 32),  256, 0, stream>>>(Wxs, WxsT, 1024, 128);
    k_transpose<<<dim3(64, 32), 256, 0, stream>>>(Wve, WveT, 1024, 2048);
    k_transpose<<<dim3(64, 32), 256, 0, stream>>>(Wue, WueT, 1024, 2048);
    k_transpose<<<dim3(32, 64), 256, 0, stream>>>(Wod, WodT, 2048, 1024);
    // z + affine variants
    k_zgemm<<<256, 256, 0, stream>>>(xb, WxsT, bxs, gamma, beta, z, qq, kq, ql);
    // k_lin transposed
    k_klinT<<<dim3(1024, 4), 256, 0, stream>>>(z, gamma, beta, klt);
    // v (staged)
    k_vgemm<<<dim3(256, 16), 256, 0, stream>>>(xb, WveT, bve, vT);
    // kv (staged GEMM, K-split x4 atomics)
    hipMemsetAsync(kvF, 0, (size_t)8 * 2048 * 128 * 4, stream);
    k_kv<<<dim3(16, 4, 8), 256, 0, stream>>>(vT, klt, kvF);
    k_kvcvt<<<2048, 256, 0, stream>>>(kvF, kvT, 8 * 2048 * 128);
    // quadratic attention scores (pure GEMM now)
    k_a<<<dim3(2, 128), 256, 0, stream>>>(qq, kq, rel_bias, a);
    // t1 = tanh(u) * (v_quad + v_lin)
    k_t1u<<<dim3(256, 16), 256, 0, stream>>>(ql, a, vT, kvT, xb, WueT, bue, t1);
    // out (staged)
    k_o<<<dim3(256, 8), 256, 0, stream>>>(t1, WodT, bod, out);
}

// Round 4
// 1035.024 us; speedup vs baseline: 1.8921x; 1.3104x over previous
//
#include <hip/hip_runtime.h>
#include <hip/hip_bf16.h>

using u16 = unsigned short;
using u32 = unsigned int;

typedef __attribute__((ext_vector_type(8))) short bf8;   // 8 x bf16 bits (4 VGPR)
typedef __attribute__((ext_vector_type(4))) float f4;    // MFMA acc
typedef __attribute__((ext_vector_type(4))) u16  us4;

#define DEV static __device__ __forceinline__

DEV float bf2f(u16 u) { return __uint_as_float(((u32)u) << 16); }
DEV u16 f2bf(float f) {
    u32 x = __float_as_uint(f);
    x += 0x7FFFu + ((x >> 16) & 1u);          // RNE
    return (u16)(x >> 16);
}
DEV float tanhf_fast(float x) {               // tanh = 1 - 2/(e^{2x}+1)
    float e = __expf(2.0f * x);
    return 1.0f - 2.0f / (e + 1.0f);
}
DEV f4 MFMA(bf8 a, bf8 b, f4 c) {
    return __builtin_amdgcn_mfma_f32_16x16x32_bf16(a, b, c, 0, 0, 0);
}
// XCD-aware bijective swizzle for grids with nwg.x % 8 == 0 (T1)
DEV int xcd_swz(int bx, int nwg) { return (bx & 7) * (nwg >> 3) + (bx >> 3); }

// ---------------- constants ----------------
// D=1024 E=2048 S_DIM=128 C=256 SRC=4096 G=16 B=8, M = B*SRC = 32768 rows
// GEMM row order r = b*4096 + s; xb stored r-major [r][1024]

// ---------------- workspace layout (bytes) ----------------
#define WS_XB    ((size_t)0)                    // bf16 x, [r][1024]                      64 MiB
#define WS_WXST  ((size_t)67108864)             // WxsT [128][1024]                       256 KiB
#define WS_WVET  ((size_t)67371008)             // WveT [2048][1024]                      4 MiB
#define WS_WUET  ((size_t)71565312)             // WueT [2048][1024]                      4 MiB
#define WS_WODT  ((size_t)75759616)             // WodT [1024][2048]                      4 MiB
#define WS_KVT   ((size_t)79953920)             // kvT bf16 [B][2048][128]                4 MiB
#define WS_A     ((size_t)84148224)             // a bf16 [128][256][256]                 16 MiB
#define WS_QL    ((size_t)100925440)            // ql bf16 [32768][128] (live in k_t1)    8 MiB
#define WS_VT    ((size_t)109314048)            // vT bf16 [B][2048][4096]                128 MiB
#define WS_T1    ((size_t)243531776)            // t1/t2 bf16 [32768][2048]               128 MiB
// --- aliases inside the t1 block: all dead before k_t1 writes t1 ---
#define WS_Z     ((size_t)243531776)            // z bf16 [32768][128]   (dead after k_klinT)  8 MiB
#define WS_KLT   ((size_t)251920384)            // klinT bf16 [B][128][4096] (dead after k_kv) 8 MiB
#define WS_QQ    ((size_t)260308992)            // qq bf16 [32768][128]  (dead after k_a)      8 MiB
#define WS_KQ    ((size_t)268697600)            // kq bf16 [32768][128]  (dead after k_a)      8 MiB
#define WS_KVF   ((size_t)277086208)            // kvF f32 [B][2048][128] (dead after k_kvcvt) 8 MiB
// total 377,749,504 bytes

// ================= staged-GEMM building blocks (m97 structure) =================
DEV void stage128x64(const u16* __restrict__ gbase, int ld, u16* lds, int w, int lane) {
    const int srow = lane >> 3;             // 0..7
    const int scol = (lane & 7) * 8;        // 0,8,..56
    #pragma unroll
    for (int i = 0; i < 4; i++) {
        const int rt = (i * 4 + w) * 8 + srow;
        const u16* src = gbase + (size_t)rt * ld + scol;
        u16* dst = lds + (size_t)(i * 4 + w) * 512;   // wave-uniform base; HW adds lane*16B
        __builtin_amdgcn_global_load_lds(
            (const __attribute__((address_space(1))) void*)src,
            (__attribute__((address_space(3))) void*)dst, 16, 0, 0);
    }
}

DEV void frag_mfma_64(const u16* As, const u16* Bs, int wm, int wn, int ln, int lh,
                      f4 acc[4][4]) {
    #pragma unroll
    for (int kk = 0; kk < 64; kk += 32) {
        bf8 a[4], b[4];
        #pragma unroll
        for (int mt = 0; mt < 4; mt++)
            a[mt] = *reinterpret_cast<const bf8*>(As + (wm * 64 + mt * 16 + ln) * 64 + kk + lh * 8);
        #pragma unroll
        for (int nt = 0; nt < 4; nt++)
            b[nt] = *reinterpret_cast<const bf8*>(Bs + (wn * 64 + nt * 16 + ln) * 64 + kk + lh * 8);
        #pragma unroll
        for (int mt = 0; mt < 4; mt++)
            #pragma unroll
            for (int nt = 0; nt < 4; nt++)
                acc[mt][nt] = MFMA(a[mt], b[nt], acc[mt][nt]);
    }
}

// ---------------- conversion kernels ----------------
// value [s][b][d] f32 -> xb [b*4096+s][d] bf16
__global__ void k_cvt_x(const float* __restrict__ src, u16* __restrict__ dst) {
    int m = blockIdx.x;                 // m = s*8 + b
    int s = m >> 3, b = m & 7;
    const float* in = src + (size_t)m * 1024;
    u16* outp = dst + (((size_t)b << 12) + s) * 1024;
    int t = threadIdx.x * 4;
    float4 v = *reinterpret_cast<const float4*>(in + t);
    us4 o; o[0] = f2bf(v.x); o[1] = f2bf(v.y); o[2] = f2bf(v.z); o[3] = f2bf(v.w);
    *reinterpret_cast<us4*>(outp + t) = o;
}

// src[R][C] f32 -> dst[C][R] bf16
__global__ void k_transpose(const float* __restrict__ src, u16* __restrict__ dst, int R, int C) {
    __shared__ u16 tile[32][33];
    int tx = threadIdx.x & 31, ty = threadIdx.x >> 5;   // 256 thr: 32x8
    int r0 = blockIdx.y * 32, c0 = blockIdx.x * 32;
    #pragma unroll
    for (int rr = ty; rr < 32; rr += 8)
        tile[rr][tx] = f2bf(src[(size_t)(r0 + rr) * C + c0 + tx]);
    __syncthreads();
    #pragma unroll
    for (int cc = ty; cc < 32; cc += 8)
        dst[(size_t)(c0 + cc) * R + r0 + tx] = tile[tx][cc];
}

// z rows -> klinT[b][s][pos] with affine (gamma3,beta3)
__global__ void k_klinT(const u16* __restrict__ z, const float* __restrict__ gamma,
                        const float* __restrict__ beta, u16* __restrict__ klt) {
    __shared__ u16 tile[32][33];
    int tx = threadIdx.x & 31, ty = threadIdx.x >> 5;
    int r0 = blockIdx.x * 32;            // global row (0..32767)
    int c0 = blockIdx.y * 32;            // s col (0..127)
    float gs = gamma[384 + c0 + tx], bs = beta[384 + c0 + tx];
    #pragma unroll
    for (int rr = ty; rr < 32; rr += 8) {
        u16 zv = z[(size_t)(r0 + rr) * 128 + c0 + tx];
        tile[rr][tx] = f2bf(bf2f(zv) * gs + bs);
    }
    __syncthreads();
    int b = r0 >> 12;
    int pos0 = r0 & 4095;
    #pragma unroll
    for (int cc = ty; cc < 32; cc += 8)
        klt[(((size_t)b * 128 + c0 + cc) << 12) + pos0 + tx] = tile[tx][cc];
}

// ---------------- z/qq/kq/ql = affine(tanh(x @ Wxs + bxs)) (staged) ----------------
__global__ __launch_bounds__(256) void k_zgemm(const u16* __restrict__ xb, const u16* __restrict__ WxsT,
                                               const float* __restrict__ bxs,
                                               const float* __restrict__ gamma, const float* __restrict__ beta,
                                               u16* __restrict__ z, u16* __restrict__ qq,
                                               u16* __restrict__ kq, u16* __restrict__ ql) {
    __shared__ u16 As[128 * 64];
    __shared__ u16 Bs[128 * 64];
    const int tid = threadIdx.x;
    const int lane = tid & 63, w = tid >> 6;
    const int ln = lane & 15, lh = lane >> 4;
    const int wm = w >> 1, wn = w & 1;
    const int rowbase = xcd_swz(blockIdx.x, 256) * 128;
    f4 acc[4][4] = {};
    for (int kt = 0; kt < 1024; kt += 64) {
        stage128x64(xb + (size_t)rowbase * 1024 + kt, 1024, As, w, lane);
        stage128x64(WxsT + kt, 1024, Bs, w, lane);
        __syncthreads();
        frag_mfma_64(As, Bs, wm, wn, ln, lh, acc);
        __syncthreads();
    }
    #pragma unroll
    for (int mt = 0; mt < 4; mt++)
        #pragma unroll
        for (int nt = 0; nt < 4; nt++) {
            int col = wn * 64 + nt * 16 + ln;
            float bias = bxs[col];
            float g0 = gamma[col],       b0 = beta[col];
            float g1 = gamma[128 + col], b1 = beta[128 + col];
            float g2 = gamma[256 + col], b2 = beta[256 + col];
            int r0 = rowbase + wm * 64 + mt * 16 + lh * 4;
            #pragma unroll
            for (int rg = 0; rg < 4; rg++) {
                float zv = tanhf_fast(acc[mt][nt][rg] + bias);
                size_t idx = ((size_t)(r0 + rg) << 7) + col;
                z[idx]  = f2bf(zv);
                qq[idx] = f2bf(zv * g0 + b0);
                kq[idx] = f2bf(zv * g1 + b1);
                ql[idx] = f2bf(zv * g2 + b2);
            }
        }
}

// ---------------- vT = tanh(x @ Wve + bve)^T : bf16 [B][2048][4096] (staged) ----------------
__global__ __launch_bounds__(256) void k_vgemm(const u16* __restrict__ xb, const u16* __restrict__ WveT,
                                               const float* __restrict__ bve, u16* __restrict__ vT) {
    __shared__ u16 As[128 * 64];
    __shared__ u16 Bs[128 * 64];
    const int tid = threadIdx.x;
    const int lane = tid & 63, w = tid >> 6;
    const int ln = lane & 15, lh = lane >> 4;
    const int wm = w >> 1, wn = w & 1;
    const int rowbase = xcd_swz(blockIdx.x, 256) * 128;
    const int colbase = blockIdx.y * 128;
    f4 acc[4][4] = {};
    for (int kt = 0; kt < 1024; kt += 64) {
        stage128x64(xb + (size_t)rowbase * 1024 + kt, 1024, As, w, lane);
        stage128x64(WveT + (size_t)colbase * 1024 + kt, 1024, Bs, w, lane);
        __syncthreads();
        frag_mfma_64(As, Bs, wm, wn, ln, lh, acc);
        __syncthreads();
    }
    #pragma unroll
    for (int mt = 0; mt < 4; mt++)
        #pragma unroll
        for (int nt = 0; nt < 4; nt++) {
            int e = colbase + wn * 64 + nt * 16 + ln;
            float bias = bve[e];
            int r0 = rowbase + wm * 64 + mt * 16 + lh * 4;
            int bb = r0 >> 12, s0 = r0 & 4095;       // 4 consecutive s, same b
            us4 p;
            #pragma unroll
            for (int rg = 0; rg < 4; rg++) p[rg] = f2bf(tanhf_fast(acc[mt][nt][rg] + bias));
            *reinterpret_cast<us4*>(vT + (((size_t)bb * 2048 + e) << 12) + s0) = p;
        }
}

// ---------------- kvF[b][e][s] += vT[b][e][kseg] @ klinT[b][s][kseg] (staged, K-split x4) ----------------
__global__ __launch_bounds__(256) void k_kv(const u16* __restrict__ vT, const u16* __restrict__ klt,
                                            float* __restrict__ kvF) {
    __shared__ u16 As[128 * 64];
    __shared__ u16 Bs[128 * 64];
    const int tid = threadIdx.x;
    const int lane = tid & 63, w = tid >> 6;
    const int ln = lane & 15, lh = lane >> 4;
    const int wm = w >> 1, wn = w & 1;
    const int b = blockIdx.z;
    const int rowbase = blockIdx.x * 128;            // e
    const int kbase = blockIdx.y * 1024;             // pos segment
    const u16* A = vT + ((size_t)b * 2048) * 4096;
    const u16* B = klt + ((size_t)b * 128) * 4096;
    f4 acc[4][4] = {};
    for (int kt = kbase; kt < kbase + 1024; kt += 64) {
        stage128x64(A + (size_t)rowbase * 4096 + kt, 4096, As, w, lane);
        stage128x64(B + kt, 4096, Bs, w, lane);
        __syncthreads();
        frag_mfma_64(As, Bs, wm, wn, ln, lh, acc);
        __syncthreads();
    }
    #pragma unroll
    for (int mt = 0; mt < 4; mt++)
        #pragma unroll
        for (int nt = 0; nt < 4; nt++) {
            int s = wn * 64 + nt * 16 + ln;
            int e0 = rowbase + wm * 64 + mt * 16 + lh * 4;
            #pragma unroll
            for (int rg = 0; rg < 4; rg++)
                atomicAdd(&kvF[(((size_t)b * 2048 + e0 + rg) << 7) + s], acc[mt][nt][rg]);
        }
}

__global__ void k_kvcvt(const float* __restrict__ kvF, u16* __restrict__ kvT, int n) {
    int i = (blockIdx.x * blockDim.x + threadIdx.x) * 4;
    if (i < n) {
        float4 v = *reinterpret_cast<const float4*>(kvF + i);
        us4 o; o[0] = f2bf(v.x); o[1] = f2bf(v.y); o[2] = f2bf(v.z); o[3] = f2bf(v.w);
        *reinterpret_cast<us4*>(kvT + i) = o;
    }
}

// ---------------- a = relu(qq @ kq^T + rel_bias)^2 : bf16 [128][256][256] (pure GEMM) ----------------
__global__ __launch_bounds__(256) void k_a(const u16* __restrict__ qq, const u16* __restrict__ kq,
                                           const float* __restrict__ rel_bias, u16* __restrict__ a_out) {
    const int lane = threadIdx.x & 63, wid = threadIdx.x >> 6;
    const int ln = lane & 15, lh = lane >> 4;
    const int wm = wid >> 1, wn = wid & 1;
    const int ci = blockIdx.y;
    const int qbase = blockIdx.x * 128 + wm * 64;    // q rows within chunk
    const int nbase = wn * 128;                      // key cols within chunk
    const int rowbase = ci << 8;
    f4 acc[4][8] = {};
    const u16* qr[4];
    #pragma unroll
    for (int mt = 0; mt < 4; mt++) qr[mt] = qq + ((size_t)(rowbase + qbase + mt * 16 + ln) << 7);
    const u16* kr[8];
    #pragma unroll
    for (int nt = 0; nt < 8; nt++) kr[nt] = kq + ((size_t)(rowbase + nbase + nt * 16 + ln) << 7);
    #pragma unroll
    for (int kk = 0; kk < 128; kk += 32) {
        int k0 = kk + lh * 8;
        bf8 aq[4], ak[8];
        #pragma unroll
        for (int mt = 0; mt < 4; mt++) aq[mt] = *reinterpret_cast<const bf8*>(qr[mt] + k0);
        #pragma unroll
        for (int nt = 0; nt < 8; nt++) ak[nt] = *reinterpret_cast<const bf8*>(kr[nt] + k0);
        #pragma unroll
        for (int mt = 0; mt < 4; mt++)
            #pragma unroll
            for (int nt = 0; nt < 8; nt++)
                acc[mt][nt] = MFMA(aq[mt], ak[nt], acc[mt][nt]);
    }
    #pragma unroll
    for (int nt = 0; nt < 8; nt++) {
        int key = nbase + nt * 16 + ln;
        float rb = rel_bias[key];
        #pragma unroll
        for (int mt = 0; mt < 4; mt++) {
            int r0 = qbase + mt * 16 + lh * 4;
            #pragma unroll
            for (int rg = 0; rg < 4; rg++) {
                float v = acc[mt][nt][rg] + rb;
                v = fmaxf(v, 0.0f); v = v * v;
                a_out[((size_t)ci << 16) + ((size_t)(r0 + rg) << 8) + key] = f2bf(v);
            }
        }
    }
}

// ---------------- t2 = ql @ kv + a @ v : bf16 [32768][2048] (fully staged) ----------------
__global__ __launch_bounds__(256) void k_t1(const u16* __restrict__ ql, const u16* __restrict__ a_in,
                                            const u16* __restrict__ vT, const u16* __restrict__ kvT,
                                            u16* __restrict__ t1) {
    __shared__ u16 As[128 * 64];
    __shared__ u16 Bs[128 * 64];
    const int tid = threadIdx.x;
    const int lane = tid & 63, w = tid >> 6;
    const int ln = lane & 15, lh = lane >> 4;
    const int wm = w >> 1, wn = w & 1;
    const int bx = xcd_swz(blockIdx.x, 256);
    const int rowbase = bx * 128;
    const int ebase = blockIdx.y * 128;
    const int ci = bx >> 1;
    const int b = ci >> 4, g = ci & 15;
    f4 acc[4][4] = {};
    // phase a: ql @ kvT^T  (K = 128)
    for (int kt = 0; kt < 128; kt += 64) {
        stage128x64(ql + (size_t)rowbase * 128 + kt, 128, As, w, lane);
        stage128x64(kvT + ((size_t)(b * 2048 + ebase)) * 128 + kt, 128, Bs, w, lane);
        __syncthreads();
        frag_mfma_64(As, Bs, wm, wn, ln, lh, acc);
        __syncthreads();
    }
    // phase b: a @ v  (K = 256 keys)
    const int lqbase = (bx & 1) * 128;
    const u16* abase = a_in + ((size_t)ci << 16) + (size_t)lqbase * 256;
    const u16* vbase = vT + ((size_t)(b * 2048 + ebase)) * 4096 + (g << 8);
    for (int kt = 0; kt < 256; kt += 64) {
        stage128x64(abase + kt, 256, As, w, lane);
        stage128x64(vbase + kt, 4096, Bs, w, lane);
        __syncthreads();
        frag_mfma_64(As, Bs, wm, wn, ln, lh, acc);
        __syncthreads();
    }
    #pragma unroll
    for (int mt = 0; mt < 4; mt++)
        #pragma unroll
        for (int nt = 0; nt < 4; nt++) {
            int e = ebase + wn * 64 + nt * 16 + ln;
            int r0 = rowbase + wm * 64 + mt * 16 + lh * 4;
            #pragma unroll
            for (int rg = 0; rg < 4; rg++)
                t1[((size_t)(r0 + rg) << 11) + e] = f2bf(acc[mt][nt][rg]);
        }
}

// ---------------- t1 = tanh(x @ Wue + bue) * t2 (in place, staged) ----------------
__global__ __launch_bounds__(256) void k_u(const u16* __restrict__ xb, const u16* __restrict__ WueT,
                                           const float* __restrict__ bue, u16* t1) {
    __shared__ u16 As[128 * 64];
    __shared__ u16 Bs[128 * 64];
    const int tid = threadIdx.x;
    const int lane = tid & 63, w = tid >> 6;
    const int ln = lane & 15, lh = lane >> 4;
    const int wm = w >> 1, wn = w & 1;
    const int rowbase = xcd_swz(blockIdx.x, 256) * 128;
    const int colbase = blockIdx.y * 128;
    f4 acc[4][4] = {};
    for (int kt = 0; kt < 1024; kt += 64) {
        stage128x64(xb + (size_t)rowbase * 1024 + kt, 1024, As, w, lane);
        stage128x64(WueT + (size_t)colbase * 1024 + kt, 1024, Bs, w, lane);
        __syncthreads();
        frag_mfma_64(As, Bs, wm, wn, ln, lh, acc);
        __syncthreads();
    }
    #pragma unroll
    for (int mt = 0; mt < 4; mt++)
        #pragma unroll
        for (int nt = 0; nt < 4; nt++) {
            int e = colbase + wn * 64 + nt * 16 + ln;
            float bias = bue[e];
            int r0 = rowbase + wm * 64 + mt * 16 + lh * 4;
            #pragma unroll
            for (int rg = 0; rg < 4; rg++) {
                size_t idx = ((size_t)(r0 + rg) << 11) + e;
                float t = bf2f(t1[idx]);
                float u = tanhf_fast(acc[mt][nt][rg] + bias);
                t1[idx] = f2bf(u * t);
            }
        }
}

// ---------------- out = t1 @ Wod + bod -> [s][b][d] f32 (staged) ----------------
__global__ __launch_bounds__(256) void k_o(const u16* __restrict__ t1, const u16* __restrict__ WodT,
                                           const float* __restrict__ bod, float* __restrict__ out) {
    __shared__ u16 As[128 * 64];
    __shared__ u16 Bs[128 * 64];
    const int tid = threadIdx.x;
    const int lane = tid & 63, w = tid >> 6;
    const int ln = lane & 15, lh = lane >> 4;
    const int wm = w >> 1, wn = w & 1;
    const int rowbase = xcd_swz(blockIdx.x, 256) * 128;
    const int colbase = blockIdx.y * 128;
    f4 acc[4][4] = {};
    for (int kt = 0; kt < 2048; kt += 64) {
        stage128x64(t1 + (size_t)rowbase * 2048 + kt, 2048, As, w, lane);
        stage128x64(WodT + (size_t)colbase * 2048 + kt, 2048, Bs, w, lane);
        __syncthreads();
        frag_mfma_64(As, Bs, wm, wn, ln, lh, acc);
        __syncthreads();
    }
    #pragma unroll
    for (int mt = 0; mt < 4; mt++)
        #pragma unroll
        for (int nt = 0; nt < 4; nt++) {
            int d = colbase + wn * 64 + nt * 16 + ln;
            float bias = bod[d];
            int r0 = rowbase + wm * 64 + mt * 16 + lh * 4;
            #pragma unroll
            for (int rg = 0; rg < 4; rg++) {
                int r = r0 + rg;
                int s = r & 4095, bb = r >> 12;
                out[((size_t)(s * 8 + bb) << 10) + d] = acc[mt][nt][rg] + bias;
            }
        }
}

extern "C" void kernel_launch(void* const* d_in, const int* in_sizes, int n_in,
                              void* d_out, int out_size, void* d_ws, size_t ws_size,
                              hipStream_t stream) {
    const float* value = (const float*)d_in[2];
    const float* Wxs = (const float*)d_in[3];  const float* bxs = (const float*)d_in[4];
    const float* Wve = (const float*)d_in[5];  const float* bve = (const float*)d_in[6];
    const float* Wue = (const float*)d_in[7];  const float* bue = (const float*)d_in[8];
    const float* Wod = (const float*)d_in[9];  const float* bod = (const float*)d_in[10];
    const float* rel_bias = (const float*)d_in[11];
    const float* gamma = (const float*)d_in[12];
    const float* beta  = (const float*)d_in[13];
    float* out = (float*)d_out;

    char* ws = (char*)d_ws;
    u16* xb   = (u16*)(ws + WS_XB);
    u16* WxsT = (u16*)(ws + WS_WXST);
    u16* WveT = (u16*)(ws + WS_WVET);
    u16* WueT = (u16*)(ws + WS_WUET);
    u16* WodT = (u16*)(ws + WS_WODT);
    u16* kvT  = (u16*)(ws + WS_KVT);
    u16* a    = (u16*)(ws + WS_A);
    u16* ql   = (u16*)(ws + WS_QL);
    u16* vT   = (u16*)(ws + WS_VT);
    u16* t1   = (u16*)(ws + WS_T1);
    u16* z    = (u16*)(ws + WS_Z);
    u16* klt  = (u16*)(ws + WS_KLT);
    u16* qq   = (u16*)(ws + WS_QQ);
    u16* kq   = (u16*)(ws + WS_KQ);
    float* kvF = (float*)(ws + WS_KVF);

    // conversions
    k_cvt_x<<<32768, 256, 0, stream>>>(value, xb);
    k_transpose<<<dim3(4, 32),  256, 0, stream>>>(Wxs, WxsT, 1024, 128);
    k_transpose<<<dim3(64, 32), 256, 0, stream>>>(Wve, WveT, 1024, 2048);
    k_transpose<<<dim3(64, 32), 256, 0, stream>>>(Wue, WueT, 1024, 2048);
    k_transpose<<<dim3(32, 64), 256, 0, stream>>>(Wod, WodT, 2048, 1024);
    // z + affine variants (staged)
    k_zgemm<<<256, 256, 0, stream>>>(xb, WxsT, bxs, gamma, beta, z, qq, kq, ql);
    // k_lin transposed
    k_klinT<<<dim3(1024, 4), 256, 0, stream>>>(z, gamma, beta, klt);
    // v (staged)
    k_vgemm<<<dim3(256, 16), 256, 0, stream>>>(xb, WveT, bve, vT);
    // kv (staged GEMM, K-split x4 atomics)
    hipMemsetAsync(kvF, 0, (size_t)8 * 2048 * 128 * 4, stream);
    k_kv<<<dim3(16, 4, 8), 256, 0, stream>>>(vT, klt, kvF);
    k_kvcvt<<<2048, 256, 0, stream>>>(kvF, kvT, 8 * 2048 * 128);
    // quadratic attention scores (pure GEMM)
    k_a<<<dim3(2, 128), 256, 0, stream>>>(qq, kq, rel_bias, a);
    // t2 = v_quad + v_lin (staged)
    k_t1<<<dim3(256, 16), 256, 0, stream>>>(ql, a, vT, kvT, t1);
    // t1 = tanh(u) * t2 (staged, in place)
    k_u<<<dim3(256, 16), 256, 0, stream>>>(xb, WueT, bue, t1);
    // out (staged)
    k_o<<<dim3(256, 8), 256, 0, stream>>>(t1, WodT, bod, out);
}

// Round 5
// 856.320 us; speedup vs baseline: 2.2870x; 1.2087x over previous
//
#include <hip/hip_runtime.h>
#include <hip/hip_bf16.h>

using u16 = unsigned short;
using u32 = unsigned int;

typedef __attribute__((ext_vector_type(8))) short bf8;   // 8 x bf16 bits (4 VGPR)
typedef __attribute__((ext_vector_type(4))) float f4;    // MFMA acc
typedef __attribute__((ext_vector_type(4))) u16  us4;

#define DEV static __device__ __forceinline__

DEV float bf2f(u16 u) { return __uint_as_float(((u32)u) << 16); }
DEV u16 f2bf(float f) {
    u32 x = __float_as_uint(f);
    x += 0x7FFFu + ((x >> 16) & 1u);          // RNE
    return (u16)(x >> 16);
}
DEV float tanhf_fast(float x) {               // tanh = 1 - 2/(e^{2x}+1)
    float e = __expf(2.0f * x);
    return 1.0f - 2.0f / (e + 1.0f);
}
DEV f4 MFMA(bf8 a, bf8 b, f4 c) {
    return __builtin_amdgcn_mfma_f32_16x16x32_bf16(a, b, c, 0, 0, 0);
}
// XCD-aware bijective swizzle for grids with nwg.x % 8 == 0 (T1)
DEV int xcd_swz(int bx, int nwg) { return (bx & 7) * (nwg >> 3) + (bx >> 3); }

// ---------------- constants ----------------
// D=1024 E=2048 S_DIM=128 C=256 SRC=4096 G=16 B=8, M = B*SRC = 32768 rows
// GEMM row order r = b*4096 + s; xb stored r-major [r][1024]

// ---------------- workspace layout (bytes) ----------------
#define WS_XB    ((size_t)0)                    // bf16 x, [r][1024]                      64 MiB
#define WS_WXST  ((size_t)67108864)             // WxsT [128][1024]                       256 KiB
#define WS_WVET  ((size_t)67371008)             // WveT [2048][1024]                      4 MiB
#define WS_WUET  ((size_t)71565312)             // WueT [2048][1024]                      4 MiB
#define WS_WODT  ((size_t)75759616)             // WodT [1024][2048]                      4 MiB
#define WS_KVT   ((size_t)79953920)             // kvT bf16 [B][2048][128]                4 MiB
#define WS_A     ((size_t)84148224)             // a bf16 [128][256][256]                 16 MiB
#define WS_QL    ((size_t)100925440)            // ql bf16 [32768][128] (live in k_t1)    8 MiB
#define WS_VT    ((size_t)109314048)            // vT bf16 [B][2048][4096]                128 MiB
#define WS_T1    ((size_t)243531776)            // t1/t2 bf16 [32768][2048]               128 MiB
// --- aliases inside the t1 block: all dead before k_t1 writes t1 ---
#define WS_Z     ((size_t)243531776)            // z bf16 [32768][128]   (dead after k_klinT)  8 MiB
#define WS_KLT   ((size_t)251920384)            // klinT bf16 [B][128][4096] (dead after k_kv) 8 MiB
#define WS_QQ    ((size_t)260308992)            // qq bf16 [32768][128]  (dead after k_a)      8 MiB
#define WS_KQ    ((size_t)268697600)            // kq bf16 [32768][128]  (dead after k_a)      8 MiB
#define WS_KVF   ((size_t)277086208)            // kvF f32 [B][2048][128] (dead after k_kvcvt) 8 MiB
// total 377,749,504 bytes

// ================= staged-GEMM building blocks =================
// tile 128x128, BK=64, 4 waves, double-buffered LDS, counted vmcnt pipeline.
// LDS layout per buffer: [128 rows][8 slots of 8 bf16], slot XOR-swizzled by (row&7).
// Write side: global_load_lds dest is linear (base+lane*16B); the SOURCE column
// is pre-swizzled by the same involution, so read-side XOR recovers the data (rule #21).

DEV void stage128x64(const u16* __restrict__ gbase, int ld, u16* lds, int w, int lane) {
    const int srow = lane >> 3;                       // 0..7
    const int scol = ((lane & 7) ^ srow) * 8;         // pre-swizzled source slot
    #pragma unroll
    for (int i = 0; i < 4; i++) {
        const int rt = (i * 4 + w) * 8 + srow;
        const u16* src = gbase + (size_t)rt * ld + scol;
        u16* dst = lds + (size_t)(i * 4 + w) * 512;   // wave-uniform base; HW adds lane*16B
        __builtin_amdgcn_global_load_lds(
            (const __attribute__((address_space(1))) void*)src,
            (__attribute__((address_space(3))) void*)dst, 16, 0, 0);
    }
}

DEV void frag_mfma_64_swz(const u16* As, const u16* Bs, int wm, int wn, int ln, int lh,
                          f4 acc[4][4]) {
    #pragma unroll
    for (int kk2 = 0; kk2 < 2; kk2++) {
        const int sx = (((kk2 << 2) + lh) ^ (ln & 7)) << 3;   // swizzled slot offset (elems)
        bf8 a[4], b[4];
        #pragma unroll
        for (int mt = 0; mt < 4; mt++)
            a[mt] = *reinterpret_cast<const bf8*>(As + (wm * 64 + mt * 16 + ln) * 64 + sx);
        #pragma unroll
        for (int nt = 0; nt < 4; nt++)
            b[nt] = *reinterpret_cast<const bf8*>(Bs + (wn * 64 + nt * 16 + ln) * 64 + sx);
        #pragma unroll
        for (int mt = 0; mt < 4; mt++)
            #pragma unroll
            for (int nt = 0; nt < 4; nt++)
                acc[mt][nt] = MFMA(a[mt], b[nt], acc[mt][nt]);
    }
}

// Pipelined K-loop: prefetch next tile while computing current; vmcnt never 0 in loop.
template<int NT, typename FA, typename FB>
DEV void gemm_pipe(FA stageA, FB stageB, u16* As, u16* Bs,
                   int wm, int wn, int ln, int lh, f4 acc[4][4]) {
    stageA(As, 0); stageB(Bs, 0);                    // 8 loads in flight
    #pragma unroll 2
    for (int t = 0; t + 1 < NT; ++t) {
        u16* An = As + ((t & 1) ^ 1) * 8192;
        u16* Bn = Bs + ((t & 1) ^ 1) * 8192;
        stageA(An, t + 1); stageB(Bn, t + 1);        // 16 in flight
        asm volatile("s_waitcnt vmcnt(8)" ::: "memory");   // oldest 8 (current tile) done
        __builtin_amdgcn_s_barrier();
        __builtin_amdgcn_sched_barrier(0);
        frag_mfma_64_swz(As + (t & 1) * 8192, Bs + (t & 1) * 8192, wm, wn, ln, lh, acc);
        __builtin_amdgcn_sched_barrier(0);
        __builtin_amdgcn_s_barrier();
        __builtin_amdgcn_sched_barrier(0);
    }
    asm volatile("s_waitcnt vmcnt(0)" ::: "memory");
    __builtin_amdgcn_s_barrier();
    frag_mfma_64_swz(As + ((NT - 1) & 1) * 8192, Bs + ((NT - 1) & 1) * 8192, wm, wn, ln, lh, acc);
    __builtin_amdgcn_s_barrier();                    // protect LDS reuse by a following phase
}

// ---------------- conversion kernels ----------------
// value [s][b][d] f32 -> xb [b*4096+s][d] bf16
__global__ void k_cvt_x(const float* __restrict__ src, u16* __restrict__ dst) {
    int m = blockIdx.x;                 // m = s*8 + b
    int s = m >> 3, b = m & 7;
    const float* in = src + (size_t)m * 1024;
    u16* outp = dst + (((size_t)b << 12) + s) * 1024;
    int t = threadIdx.x * 4;
    float4 v = *reinterpret_cast<const float4*>(in + t);
    us4 o; o[0] = f2bf(v.x); o[1] = f2bf(v.y); o[2] = f2bf(v.z); o[3] = f2bf(v.w);
    *reinterpret_cast<us4*>(outp + t) = o;
}

// src[R][C] f32 -> dst[C][R] bf16
__global__ void k_transpose(const float* __restrict__ src, u16* __restrict__ dst, int R, int C) {
    __shared__ u16 tile[32][33];
    int tx = threadIdx.x & 31, ty = threadIdx.x >> 5;   // 256 thr: 32x8
    int r0 = blockIdx.y * 32, c0 = blockIdx.x * 32;
    #pragma unroll
    for (int rr = ty; rr < 32; rr += 8)
        tile[rr][tx] = f2bf(src[(size_t)(r0 + rr) * C + c0 + tx]);
    __syncthreads();
    #pragma unroll
    for (int cc = ty; cc < 32; cc += 8)
        dst[(size_t)(c0 + cc) * R + r0 + tx] = tile[tx][cc];
}

// z rows -> klinT[b][s][pos] with affine (gamma3,beta3)
__global__ void k_klinT(const u16* __restrict__ z, const float* __restrict__ gamma,
                        const float* __restrict__ beta, u16* __restrict__ klt) {
    __shared__ u16 tile[32][33];
    int tx = threadIdx.x & 31, ty = threadIdx.x >> 5;
    int r0 = blockIdx.x * 32;            // global row (0..32767)
    int c0 = blockIdx.y * 32;            // s col (0..127)
    float gs = gamma[384 + c0 + tx], bs = beta[384 + c0 + tx];
    #pragma unroll
    for (int rr = ty; rr < 32; rr += 8) {
        u16 zv = z[(size_t)(r0 + rr) * 128 + c0 + tx];
        tile[rr][tx] = f2bf(bf2f(zv) * gs + bs);
    }
    __syncthreads();
    int b = r0 >> 12;
    int pos0 = r0 & 4095;
    #pragma unroll
    for (int cc = ty; cc < 32; cc += 8)
        klt[(((size_t)b * 128 + c0 + cc) << 12) + pos0 + tx] = tile[tx][cc];
}

// ---------------- z/qq/kq/ql = affine(tanh(x @ Wxs + bxs)) (pipelined) ----------------
__global__ __launch_bounds__(256) void k_zgemm(const u16* __restrict__ xb, const u16* __restrict__ WxsT,
                                               const float* __restrict__ bxs,
                                               const float* __restrict__ gamma, const float* __restrict__ beta,
                                               u16* __restrict__ z, u16* __restrict__ qq,
                                               u16* __restrict__ kq, u16* __restrict__ ql) {
    __shared__ u16 As[2][128 * 64];
    __shared__ u16 Bs[2][128 * 64];
    const int tid = threadIdx.x;
    const int lane = tid & 63, w = tid >> 6;
    const int ln = lane & 15, lh = lane >> 4;
    const int wm = w >> 1, wn = w & 1;
    const int rowbase = xcd_swz(blockIdx.x, 256) * 128;
    const u16* Ab = xb + (size_t)rowbase * 1024;
    f4 acc[4][4] = {};
    gemm_pipe<16>(
        [&](u16* l, int t) { stage128x64(Ab + t * 64, 1024, l, w, lane); },
        [&](u16* l, int t) { stage128x64(WxsT + t * 64, 1024, l, w, lane); },
        As[0], Bs[0], wm, wn, ln, lh, acc);
    #pragma unroll
    for (int mt = 0; mt < 4; mt++)
        #pragma unroll
        for (int nt = 0; nt < 4; nt++) {
            int col = wn * 64 + nt * 16 + ln;
            float bias = bxs[col];
            float g0 = gamma[col],       b0 = beta[col];
            float g1 = gamma[128 + col], b1 = beta[128 + col];
            float g2 = gamma[256 + col], b2 = beta[256 + col];
            int r0 = rowbase + wm * 64 + mt * 16 + lh * 4;
            #pragma unroll
            for (int rg = 0; rg < 4; rg++) {
                float zv = tanhf_fast(acc[mt][nt][rg] + bias);
                size_t idx = ((size_t)(r0 + rg) << 7) + col;
                z[idx]  = f2bf(zv);
                qq[idx] = f2bf(zv * g0 + b0);
                kq[idx] = f2bf(zv * g1 + b1);
                ql[idx] = f2bf(zv * g2 + b2);
            }
        }
}

// ---------------- vT = tanh(x @ Wve + bve)^T : bf16 [B][2048][4096] (pipelined) ----------------
__global__ __launch_bounds__(256) void k_vgemm(const u16* __restrict__ xb, const u16* __restrict__ WveT,
                                               const float* __restrict__ bve, u16* __restrict__ vT) {
    __shared__ u16 As[2][128 * 64];
    __shared__ u16 Bs[2][128 * 64];
    const int tid = threadIdx.x;
    const int lane = tid & 63, w = tid >> 6;
    const int ln = lane & 15, lh = lane >> 4;
    const int wm = w >> 1, wn = w & 1;
    const int rowbase = xcd_swz(blockIdx.x, 256) * 128;
    const int colbase = blockIdx.y * 128;
    const u16* Ab = xb + (size_t)rowbase * 1024;
    const u16* Bb = WveT + (size_t)colbase * 1024;
    f4 acc[4][4] = {};
    gemm_pipe<16>(
        [&](u16* l, int t) { stage128x64(Ab + t * 64, 1024, l, w, lane); },
        [&](u16* l, int t) { stage128x64(Bb + t * 64, 1024, l, w, lane); },
        As[0], Bs[0], wm, wn, ln, lh, acc);
    #pragma unroll
    for (int mt = 0; mt < 4; mt++)
        #pragma unroll
        for (int nt = 0; nt < 4; nt++) {
            int e = colbase + wn * 64 + nt * 16 + ln;
            float bias = bve[e];
            int r0 = rowbase + wm * 64 + mt * 16 + lh * 4;
            int bb = r0 >> 12, s0 = r0 & 4095;       // 4 consecutive s, same b
            us4 p;
            #pragma unroll
            for (int rg = 0; rg < 4; rg++) p[rg] = f2bf(tanhf_fast(acc[mt][nt][rg] + bias));
            *reinterpret_cast<us4*>(vT + (((size_t)bb * 2048 + e) << 12) + s0) = p;
        }
}

// ---------------- kvF[b][e][s] += vT[b][e][kseg] @ klinT[b][s][kseg] (pipelined, K-split x4) --------
__global__ __launch_bounds__(256) void k_kv(const u16* __restrict__ vT, const u16* __restrict__ klt,
                                            float* __restrict__ kvF) {
    __shared__ u16 As[2][128 * 64];
    __shared__ u16 Bs[2][128 * 64];
    const int tid = threadIdx.x;
    const int lane = tid & 63, w = tid >> 6;
    const int ln = lane & 15, lh = lane >> 4;
    const int wm = w >> 1, wn = w & 1;
    const int b = blockIdx.z;
    const int rowbase = blockIdx.x * 128;            // e
    const int kbase = blockIdx.y * 1024;             // pos segment
    const u16* Ab = vT + ((size_t)b * 2048 + rowbase) * 4096 + kbase;
    const u16* Bb = klt + ((size_t)b * 128) * 4096 + kbase;
    f4 acc[4][4] = {};
    gemm_pipe<16>(
        [&](u16* l, int t) { stage128x64(Ab + t * 64, 4096, l, w, lane); },
        [&](u16* l, int t) { stage128x64(Bb + t * 64, 4096, l, w, lane); },
        As[0], Bs[0], wm, wn, ln, lh, acc);
    #pragma unroll
    for (int mt = 0; mt < 4; mt++)
        #pragma unroll
        for (int nt = 0; nt < 4; nt++) {
            int s = wn * 64 + nt * 16 + ln;
            int e0 = rowbase + wm * 64 + mt * 16 + lh * 4;
            #pragma unroll
            for (int rg = 0; rg < 4; rg++)
                atomicAdd(&kvF[(((size_t)b * 2048 + e0 + rg) << 7) + s], acc[mt][nt][rg]);
        }
}

__global__ void k_kvcvt(const float* __restrict__ kvF, u16* __restrict__ kvT, int n) {
    int i = (blockIdx.x * blockDim.x + threadIdx.x) * 4;
    if (i < n) {
        float4 v = *reinterpret_cast<const float4*>(kvF + i);
        us4 o; o[0] = f2bf(v.x); o[1] = f2bf(v.y); o[2] = f2bf(v.z); o[3] = f2bf(v.w);
        *reinterpret_cast<us4*>(kvT + i) = o;
    }
}

// ---------------- a = relu(qq @ kq^T + rel_bias)^2 : bf16 [128][256][256] (pure GEMM) ----------------
__global__ __launch_bounds__(256) void k_a(const u16* __restrict__ qq, const u16* __restrict__ kq,
                                           const float* __restrict__ rel_bias, u16* __restrict__ a_out) {
    const int lane = threadIdx.x & 63, wid = threadIdx.x >> 6;
    const int ln = lane & 15, lh = lane >> 4;
    const int wm = wid >> 1, wn = wid & 1;
    const int ci = blockIdx.y;
    const int qbase = blockIdx.x * 128 + wm * 64;    // q rows within chunk
    const int nbase = wn * 128;                      // key cols within chunk
    const int rowbase = ci << 8;
    f4 acc[4][8] = {};
    const u16* qr[4];
    #pragma unroll
    for (int mt = 0; mt < 4; mt++) qr[mt] = qq + ((size_t)(rowbase + qbase + mt * 16 + ln) << 7);
    const u16* kr[8];
    #pragma unroll
    for (int nt = 0; nt < 8; nt++) kr[nt] = kq + ((size_t)(rowbase + nbase + nt * 16 + ln) << 7);
    #pragma unroll
    for (int kk = 0; kk < 128; kk += 32) {
        int k0 = kk + lh * 8;
        bf8 aq[4], ak[8];
        #pragma unroll
        for (int mt = 0; mt < 4; mt++) aq[mt] = *reinterpret_cast<const bf8*>(qr[mt] + k0);
        #pragma unroll
        for (int nt = 0; nt < 8; nt++) ak[nt] = *reinterpret_cast<const bf8*>(kr[nt] + k0);
        #pragma unroll
        for (int mt = 0; mt < 4; mt++)
            #pragma unroll
            for (int nt = 0; nt < 8; nt++)
                acc[mt][nt] = MFMA(aq[mt], ak[nt], acc[mt][nt]);
    }
    #pragma unroll
    for (int nt = 0; nt < 8; nt++) {
        int key = nbase + nt * 16 + ln;
        float rb = rel_bias[key];
        #pragma unroll
        for (int mt = 0; mt < 4; mt++) {
            int r0 = qbase + mt * 16 + lh * 4;
            #pragma unroll
            for (int rg = 0; rg < 4; rg++) {
                float v = acc[mt][nt][rg] + rb;
                v = fmaxf(v, 0.0f); v = v * v;
                a_out[((size_t)ci << 16) + ((size_t)(r0 + rg) << 8) + key] = f2bf(v);
            }
        }
    }
}

// ---------------- t2 = ql @ kv + a @ v : bf16 [32768][2048] (pipelined) ----------------
__global__ __launch_bounds__(256) void k_t1(const u16* __restrict__ ql, const u16* __restrict__ a_in,
                                            const u16* __restrict__ vT, const u16* __restrict__ kvT,
                                            u16* __restrict__ t1) {
    __shared__ u16 As[2][128 * 64];
    __shared__ u16 Bs[2][128 * 64];
    const int tid = threadIdx.x;
    const int lane = tid & 63, w = tid >> 6;
    const int ln = lane & 15, lh = lane >> 4;
    const int wm = w >> 1, wn = w & 1;
    const int bx = xcd_swz(blockIdx.x, 256);
    const int rowbase = bx * 128;
    const int ebase = blockIdx.y * 128;
    const int ci = bx >> 1;
    const int b = ci >> 4, g = ci & 15;
    f4 acc[4][4] = {};
    // phase a: ql @ kvT^T  (K = 128)
    {
        const u16* Ab = ql + (size_t)rowbase * 128;
        const u16* Bb = kvT + ((size_t)(b * 2048 + ebase)) * 128;
        gemm_pipe<2>(
            [&](u16* l, int t) { stage128x64(Ab + t * 64, 128, l, w, lane); },
            [&](u16* l, int t) { stage128x64(Bb + t * 64, 128, l, w, lane); },
            As[0], Bs[0], wm, wn, ln, lh, acc);
    }
    // phase b: a @ v  (K = 256 keys)
    {
        const int lqbase = (bx & 1) * 128;
        const u16* Ab = a_in + ((size_t)ci << 16) + (size_t)lqbase * 256;
        const u16* Bb = vT + ((size_t)(b * 2048 + ebase)) * 4096 + (g << 8);
        gemm_pipe<4>(
            [&](u16* l, int t) { stage128x64(Ab + t * 64, 256, l, w, lane); },
            [&](u16* l, int t) { stage128x64(Bb + t * 64, 4096, l, w, lane); },
            As[0], Bs[0], wm, wn, ln, lh, acc);
    }
    #pragma unroll
    for (int mt = 0; mt < 4; mt++)
        #pragma unroll
        for (int nt = 0; nt < 4; nt++) {
            int e = ebase + wn * 64 + nt * 16 + ln;
            int r0 = rowbase + wm * 64 + mt * 16 + lh * 4;
            #pragma unroll
            for (int rg = 0; rg < 4; rg++)
                t1[((size_t)(r0 + rg) << 11) + e] = f2bf(acc[mt][nt][rg]);
        }
}

// ---------------- t1 = tanh(x @ Wue + bue) * t2 (in place, pipelined) ----------------
__global__ __launch_bounds__(256) void k_u(const u16* __restrict__ xb, const u16* __restrict__ WueT,
                                           const float* __restrict__ bue, u16* t1) {
    __shared__ u16 As[2][128 * 64];
    __shared__ u16 Bs[2][128 * 64];
    const int tid = threadIdx.x;
    const int lane = tid & 63, w = tid >> 6;
    const int ln = lane & 15, lh = lane >> 4;
    const int wm = w >> 1, wn = w & 1;
    const int rowbase = xcd_swz(blockIdx.x, 256) * 128;
    const int colbase = blockIdx.y * 128;
    const u16* Ab = xb + (size_t)rowbase * 1024;
    const u16* Bb = WueT + (size_t)colbase * 1024;
    f4 acc[4][4] = {};
    gemm_pipe<16>(
        [&](u16* l, int t) { stage128x64(Ab + t * 64, 1024, l, w, lane); },
        [&](u16* l, int t) { stage128x64(Bb + t * 64, 1024, l, w, lane); },
        As[0], Bs[0], wm, wn, ln, lh, acc);
    #pragma unroll
    for (int mt = 0; mt < 4; mt++)
        #pragma unroll
        for (int nt = 0; nt < 4; nt++) {
            int e = colbase + wn * 64 + nt * 16 + ln;
            float bias = bue[e];
            int r0 = rowbase + wm * 64 + mt * 16 + lh * 4;
            #pragma unroll
            for (int rg = 0; rg < 4; rg++) {
                size_t idx = ((size_t)(r0 + rg) << 11) + e;
                float t = bf2f(t1[idx]);
                float u = tanhf_fast(acc[mt][nt][rg] + bias);
                t1[idx] = f2bf(u * t);
            }
        }
}

// ---------------- out = t1 @ Wod + bod -> [s][b][d] f32 (pipelined) ----------------
__global__ __launch_bounds__(256) void k_o(const u16* __restrict__ t1, const u16* __restrict__ WodT,
                                           const float* __restrict__ bod, float* __restrict__ out) {
    __shared__ u16 As[2][128 * 64];
    __shared__ u16 Bs[2][128 * 64];
    const int tid = threadIdx.x;
    const int lane = tid & 63, w = tid >> 6;
    const int ln = lane & 15, lh = lane >> 4;
    const int wm = w >> 1, wn = w & 1;
    const int rowbase = xcd_swz(blockIdx.x, 256) * 128;
    const int colbase = blockIdx.y * 128;
    const u16* Ab = t1 + (size_t)rowbase * 2048;
    const u16* Bb = WodT + (size_t)colbase * 2048;
    f4 acc[4][4] = {};
    gemm_pipe<32>(
        [&](u16* l, int t) { stage128x64(Ab + t * 64, 2048, l, w, lane); },
        [&](u16* l, int t) { stage128x64(Bb + t * 64, 2048, l, w, lane); },
        As[0], Bs[0], wm, wn, ln, lh, acc);
    #pragma unroll
    for (int mt = 0; mt < 4; mt++)
        #pragma unroll
        for (int nt = 0; nt < 4; nt++) {
            int d = colbase + wn * 64 + nt * 16 + ln;
            float bias = bod[d];
            int r0 = rowbase + wm * 64 + mt * 16 + lh * 4;
            #pragma unroll
            for (int rg = 0; rg < 4; rg++) {
                int r = r0 + rg;
                int s = r & 4095, bb = r >> 12;
                out[((size_t)(s * 8 + bb) << 10) + d] = acc[mt][nt][rg] + bias;
            }
        }
}

extern "C" void kernel_launch(void* const* d_in, const int* in_sizes, int n_in,
                              void* d_out, int out_size, void* d_ws, size_t ws_size,
                              hipStream_t stream) {
    const float* value = (const float*)d_in[2];
    const float* Wxs = (const float*)d_in[3];  const float* bxs = (const float*)d_in[4];
    const float* Wve = (const float*)d_in[5];  const float* bve = (const float*)d_in[6];
    const float* Wue = (const float*)d_in[7];  const float* bue = (const float*)d_in[8];
    const float* Wod = (const float*)d_in[9];  const float* bod = (const float*)d_in[10];
    const float* rel_bias = (const float*)d_in[11];
    const float* gamma = (const float*)d_in[12];
    const float* beta  = (const float*)d_in[13];
    float* out = (float*)d_out;

    char* ws = (char*)d_ws;
    u16* xb   = (u16*)(ws + WS_XB);
    u16* WxsT = (u16*)(ws + WS_WXST);
    u16* WveT = (u16*)(ws + WS_WVET);
    u16* WueT = (u16*)(ws + WS_WUET);
    u16* WodT = (u16*)(ws + WS_WODT);
    u16* kvT  = (u16*)(ws + WS_KVT);
    u16* a    = (u16*)(ws + WS_A);
    u16* ql   = (u16*)(ws + WS_QL);
    u16* vT   = (u16*)(ws + WS_VT);
    u16* t1   = (u16*)(ws + WS_T1);
    u16* z    = (u16*)(ws + WS_Z);
    u16* klt  = (u16*)(ws + WS_KLT);
    u16* qq   = (u16*)(ws + WS_QQ);
    u16* kq   = (u16*)(ws + WS_KQ);
    float* kvF = (float*)(ws + WS_KVF);

    // conversions
    k_cvt_x<<<32768, 256, 0, stream>>>(value, xb);
    k_transpose<<<dim3(4, 32),  256, 0, stream>>>(Wxs, WxsT, 1024, 128);
    k_transpose<<<dim3(64, 32), 256, 0, stream>>>(Wve, WveT, 1024, 2048);
    k_transpose<<<dim3(64, 32), 256, 0, stream>>>(Wue, WueT, 1024, 2048);
    k_transpose<<<dim3(32, 64), 256, 0, stream>>>(Wod, WodT, 2048, 1024);
    // z + affine variants (pipelined)
    k_zgemm<<<256, 256, 0, stream>>>(xb, WxsT, bxs, gamma, beta, z, qq, kq, ql);
    // k_lin transposed
    k_klinT<<<dim3(1024, 4), 256, 0, stream>>>(z, gamma, beta, klt);
    // v (pipelined)
    k_vgemm<<<dim3(256, 16), 256, 0, stream>>>(xb, WveT, bve, vT);
    // kv (pipelined GEMM, K-split x4 atomics)
    hipMemsetAsync(kvF, 0, (size_t)8 * 2048 * 128 * 4, stream);
    k_kv<<<dim3(16, 4, 8), 256, 0, stream>>>(vT, klt, kvF);
    k_kvcvt<<<2048, 256, 0, stream>>>(kvF, kvT, 8 * 2048 * 128);
    // quadratic attention scores (pure GEMM)
    k_a<<<dim3(2, 128), 256, 0, stream>>>(qq, kq, rel_bias, a);
    // t2 = v_quad + v_lin (pipelined)
    k_t1<<<dim3(256, 16), 256, 0, stream>>>(ql, a, vT, kvT, t1);
    // t1 = tanh(u) * t2 (pipelined, in place)
    k_u<<<dim3(256, 16), 256, 0, stream>>>(xb, WueT, bue, t1);
    // out (pipelined)
    k_o<<<dim3(256, 8), 256, 0, stream>>>(t1, WodT, bod, out);
}

// Round 6
// 768.842 us; speedup vs baseline: 2.5472x; 1.1138x over previous
//
#include <hip/hip_runtime.h>
#include <hip/hip_bf16.h>

using u16 = unsigned short;
using u32 = unsigned int;

typedef __attribute__((ext_vector_type(8))) short bf8;   // 8 x bf16 bits (4 VGPR)
typedef __attribute__((ext_vector_type(4))) float f4;    // MFMA acc
typedef __attribute__((ext_vector_type(4))) u16  us4;

#define DEV static __device__ __forceinline__

DEV float bf2f(u16 u) { return __uint_as_float(((u32)u) << 16); }
DEV u16 f2bf(float f) {
    u32 x = __float_as_uint(f);
    x += 0x7FFFu + ((x >> 16) & 1u);          // RNE
    return (u16)(x >> 16);
}
DEV float tanhf_fast(float x) {               // tanh = 1 - 2/(e^{2x}+1)
    float e = __expf(2.0f * x);
    return 1.0f - 2.0f / (e + 1.0f);
}
DEV f4 MFMA(bf8 a, bf8 b, f4 c) {
    return __builtin_amdgcn_mfma_f32_16x16x32_bf16(a, b, c, 0, 0, 0);
}
// XCD-aware bijective swizzle for grids with nwg.x % 8 == 0 (T1)
DEV int xcd_swz(int bx, int nwg) { return (bx & 7) * (nwg >> 3) + (bx >> 3); }

DEV void gload16(const u16* src, u16* dst) {
    __builtin_amdgcn_global_load_lds(
        (const __attribute__((address_space(1))) void*)src,
        (__attribute__((address_space(3))) void*)dst, 16, 0, 0);
}

// ---------------- constants ----------------
// D=1024 E=2048 S_DIM=128 C=256 SRC=4096 G=16 B=8, M = B*SRC = 32768 rows
// GEMM row order r = b*4096 + s; xb stored r-major [r][1024]

// ---------------- workspace layout (bytes) ----------------
#define WS_XB    ((size_t)0)                    // bf16 x, [r][1024]                      64 MiB
#define WS_WXST  ((size_t)67108864)             // WxsT [128][1024]                       256 KiB
#define WS_WVET  ((size_t)67371008)             // WveT [2048][1024]                      4 MiB
#define WS_WUET  ((size_t)71565312)             // WueT [2048][1024]                      4 MiB
#define WS_WODT  ((size_t)75759616)             // WodT [1024][2048]                      4 MiB
#define WS_KVT   ((size_t)79953920)             // kvT bf16 [B][2048][128]                4 MiB
#define WS_A     ((size_t)84148224)             // a bf16 [128][256][256]                 16 MiB
#define WS_QL    ((size_t)100925440)            // ql bf16 [32768][128] (live in k_t1)    8 MiB
#define WS_VT    ((size_t)109314048)            // vT bf16 [B][2048][4096]                128 MiB
#define WS_T1    ((size_t)243531776)            // t1/t2 bf16 [32768][2048]               128 MiB
// --- aliases inside the t1 block: all dead before k_t1 writes t1 ---
#define WS_Z     ((size_t)243531776)            // z bf16 [32768][128]   (dead after k_klinT)  8 MiB
#define WS_KLT   ((size_t)251920384)            // klinT bf16 [B][128][4096] (dead after k_kv) 8 MiB
#define WS_QQ    ((size_t)260308992)            // qq bf16 [32768][128]  (dead after k_a)      8 MiB
#define WS_KQ    ((size_t)268697600)            // kq bf16 [32768][128]  (dead after k_a)      8 MiB
#define WS_KVF   ((size_t)277086208)            // kvF f32 [B][2048][128] (dead after k_kvcvt) 8 MiB
// total 377,749,504 bytes

// ================= 128^2 staged-GEMM building blocks (for k_zgemm / k_kv) =================
DEV void stage128x64(const u16* __restrict__ gbase, int ld, u16* lds, int w, int lane) {
    const int srow = lane >> 3;                       // 0..7
    const int scol = ((lane & 7) ^ srow) * 8;         // pre-swizzled source slot
    #pragma unroll
    for (int i = 0; i < 4; i++) {
        const int rt = (i * 4 + w) * 8 + srow;
        const u16* src = gbase + (size_t)rt * ld + scol;
        u16* dst = lds + (size_t)(i * 4 + w) * 512;   // wave-uniform base; HW adds lane*16B
        gload16(src, dst);
    }
}

DEV void frag_mfma_64_swz(const u16* As, const u16* Bs, int wm, int wn, int ln, int lh,
                          f4 acc[4][4]) {
    #pragma unroll
    for (int kk2 = 0; kk2 < 2; kk2++) {
        const int sx = (((kk2 << 2) + lh) ^ (ln & 7)) << 3;   // swizzled slot offset (elems)
        bf8 a[4], b[4];
        #pragma unroll
        for (int mt = 0; mt < 4; mt++)
            a[mt] = *reinterpret_cast<const bf8*>(As + (wm * 64 + mt * 16 + ln) * 64 + sx);
        #pragma unroll
        for (int nt = 0; nt < 4; nt++)
            b[nt] = *reinterpret_cast<const bf8*>(Bs + (wn * 64 + nt * 16 + ln) * 64 + sx);
        #pragma unroll
        for (int mt = 0; mt < 4; mt++)
            #pragma unroll
            for (int nt = 0; nt < 4; nt++)
                acc[mt][nt] = MFMA(a[mt], b[nt], acc[mt][nt]);
    }
}

template<int NT, typename FA, typename FB>
DEV void gemm_pipe(FA stageA, FB stageB, u16* As, u16* Bs,
                   int wm, int wn, int ln, int lh, f4 acc[4][4]) {
    stageA(As, 0); stageB(Bs, 0);                    // 8 loads in flight
    #pragma unroll 2
    for (int t = 0; t + 1 < NT; ++t) {
        u16* An = As + ((t & 1) ^ 1) * 8192;
        u16* Bn = Bs + ((t & 1) ^ 1) * 8192;
        stageA(An, t + 1); stageB(Bn, t + 1);        // 16 in flight
        asm volatile("s_waitcnt vmcnt(8)" ::: "memory");   // oldest 8 (current tile) done
        __builtin_amdgcn_s_barrier();
        __builtin_amdgcn_sched_barrier(0);
        frag_mfma_64_swz(As + (t & 1) * 8192, Bs + (t & 1) * 8192, wm, wn, ln, lh, acc);
        __builtin_amdgcn_sched_barrier(0);
        __builtin_amdgcn_s_barrier();
        __builtin_amdgcn_sched_barrier(0);
    }
    asm volatile("s_waitcnt vmcnt(0)" ::: "memory");
    __builtin_amdgcn_s_barrier();
    frag_mfma_64_swz(As + ((NT - 1) & 1) * 8192, Bs + ((NT - 1) & 1) * 8192, wm, wn, ln, lh, acc);
    __builtin_amdgcn_s_barrier();
}

// ================= 256^2 deep-tile building blocks (8 waves, 512 thr) =================
// LDS per buffer: A[256][64] + B[256][64] bf16 (32KB+32KB); 2 buffers = 128 KiB.
// wave (wm,wn): wm=w>>2 (2 M-halves of 128 rows), wn=w&3 (4 N-quarters of 64 cols).

#define T256 16384   // elements per 256x64 tile

// stage a 256x64 tile (row-major, stride ld): 4 x gload16 per thread (512 thr)
DEV void stage256x64(const u16* __restrict__ gbase, int ld, u16* lds, int tid) {
    const int slot = tid & 7;
    #pragma unroll
    for (int i = 0; i < 4; i++) {
        const int row = i * 64 + (tid >> 3);
        const u16* src = gbase + (size_t)row * ld + ((slot ^ (row & 7)) << 3);
        u16* dst = lds + ((size_t)(i * 512 + (tid & ~63)) << 3);  // wave-uniform; HW adds lane*16B
        gload16(src, dst);
    }
}

// one K-tile (BK=64) of MFMA for this wave: 64 MFMA in 4 phases of 16
DEV void tile_mfma256(const u16* As, const u16* Bs, int wm, int wn, int ln, int lh,
                      f4 acc[8][4]) {
    __builtin_amdgcn_s_setprio(1);
    #pragma unroll
    for (int p = 0; p < 4; p++) {
        const int mg = p >> 1, ks = p & 1;
        const int sx = (((ks << 2) + lh) ^ (ln & 7)) << 3;
        bf8 a[4], b[4];
        #pragma unroll
        for (int j = 0; j < 4; j++)
            a[j] = *reinterpret_cast<const bf8*>(As + (wm * 128 + (mg * 4 + j) * 16 + ln) * 64 + sx);
        #pragma unroll
        for (int n = 0; n < 4; n++)
            b[n] = *reinterpret_cast<const bf8*>(Bs + (wn * 64 + n * 16 + ln) * 64 + sx);
        #pragma unroll
        for (int j = 0; j < 4; j++)
            #pragma unroll
            for (int n = 0; n < 4; n++)
                acc[mg * 4 + j][n] = MFMA(a[j], b[n], acc[mg * 4 + j][n]);
        __builtin_amdgcn_sched_barrier(0);
    }
    __builtin_amdgcn_s_setprio(0);
}

// counted-vmcnt double-buffered pipeline; stage issues exactly 8 loads/wave per tile
template<int NT, typename F>
DEV void gemm_pipe256(F stage, u16* As, u16* Bs, int wm, int wn, int ln, int lh,
                      f4 acc[8][4]) {
    stage(As, Bs, 0);                                // 8 loads in flight
    #pragma unroll 2
    for (int t = 0; t + 1 < NT; ++t) {
        const int cur = t & 1, nxt = cur ^ 1;
        stage(As + nxt * T256, Bs + nxt * T256, t + 1);   // 16 in flight
        asm volatile("s_waitcnt vmcnt(8)" ::: "memory");  // tile t resident
        __builtin_amdgcn_s_barrier();
        __builtin_amdgcn_sched_barrier(0);
        tile_mfma256(As + cur * T256, Bs + cur * T256, wm, wn, ln, lh, acc);
        __builtin_amdgcn_sched_barrier(0);
        __builtin_amdgcn_s_barrier();                     // all waves done reading buf cur
        __builtin_amdgcn_sched_barrier(0);
    }
    asm volatile("s_waitcnt vmcnt(0)" ::: "memory");
    __builtin_amdgcn_s_barrier();
    tile_mfma256(As + ((NT - 1) & 1) * T256, Bs + ((NT - 1) & 1) * T256, wm, wn, ln, lh, acc);
    __builtin_amdgcn_s_barrier();
}

// ---------------- conversion kernels ----------------
// value [s][b][d] f32 -> xb [b*4096+s][d] bf16
__global__ void k_cvt_x(const float* __restrict__ src, u16* __restrict__ dst) {
    int m = blockIdx.x;                 // m = s*8 + b
    int s = m >> 3, b = m & 7;
    const float* in = src + (size_t)m * 1024;
    u16* outp = dst + (((size_t)b << 12) + s) * 1024;
    int t = threadIdx.x * 4;
    float4 v = *reinterpret_cast<const float4*>(in + t);
    us4 o; o[0] = f2bf(v.x); o[1] = f2bf(v.y); o[2] = f2bf(v.z); o[3] = f2bf(v.w);
    *reinterpret_cast<us4*>(outp + t) = o;
}

// src[R][C] f32 -> dst[C][R] bf16
__global__ void k_transpose(const float* __restrict__ src, u16* __restrict__ dst, int R, int C) {
    __shared__ u16 tile[32][33];
    int tx = threadIdx.x & 31, ty = threadIdx.x >> 5;   // 256 thr: 32x8
    int r0 = blockIdx.y * 32, c0 = blockIdx.x * 32;
    #pragma unroll
    for (int rr = ty; rr < 32; rr += 8)
        tile[rr][tx] = f2bf(src[(size_t)(r0 + rr) * C + c0 + tx]);
    __syncthreads();
    #pragma unroll
    for (int cc = ty; cc < 32; cc += 8)
        dst[(size_t)(c0 + cc) * R + r0 + tx] = tile[tx][cc];
}

// z rows -> klinT[b][s][pos] with affine (gamma3,beta3)
__global__ void k_klinT(const u16* __restrict__ z, const float* __restrict__ gamma,
                        const float* __restrict__ beta, u16* __restrict__ klt) {
    __shared__ u16 tile[32][33];
    int tx = threadIdx.x & 31, ty = threadIdx.x >> 5;
    int r0 = blockIdx.x * 32;            // global row (0..32767)
    int c0 = blockIdx.y * 32;            // s col (0..127)
    float gs = gamma[384 + c0 + tx], bs = beta[384 + c0 + tx];
    #pragma unroll
    for (int rr = ty; rr < 32; rr += 8) {
        u16 zv = z[(size_t)(r0 + rr) * 128 + c0 + tx];
        tile[rr][tx] = f2bf(bf2f(zv) * gs + bs);
    }
    __syncthreads();
    int b = r0 >> 12;
    int pos0 = r0 & 4095;
    #pragma unroll
    for (int cc = ty; cc < 32; cc += 8)
        klt[(((size_t)b * 128 + c0 + cc) << 12) + pos0 + tx] = tile[tx][cc];
}

// ---------------- z/qq/kq/ql = affine(tanh(x @ Wxs + bxs)) (pipelined 128^2) ----------------
__global__ __launch_bounds__(256) void k_zgemm(const u16* __restrict__ xb, const u16* __restrict__ WxsT,
                                               const float* __restrict__ bxs,
                                               const float* __restrict__ gamma, const float* __restrict__ beta,
                                               u16* __restrict__ z, u16* __restrict__ qq,
                                               u16* __restrict__ kq, u16* __restrict__ ql) {
    __shared__ u16 As[2][128 * 64];
    __shared__ u16 Bs[2][128 * 64];
    const int tid = threadIdx.x;
    const int lane = tid & 63, w = tid >> 6;
    const int ln = lane & 15, lh = lane >> 4;
    const int wm = w >> 1, wn = w & 1;
    const int rowbase = xcd_swz(blockIdx.x, 256) * 128;
    const u16* Ab = xb + (size_t)rowbase * 1024;
    f4 acc[4][4] = {};
    gemm_pipe<16>(
        [&](u16* l, int t) { stage128x64(Ab + t * 64, 1024, l, w, lane); },
        [&](u16* l, int t) { stage128x64(WxsT + t * 64, 1024, l, w, lane); },
        As[0], Bs[0], wm, wn, ln, lh, acc);
    #pragma unroll
    for (int mt = 0; mt < 4; mt++)
        #pragma unroll
        for (int nt = 0; nt < 4; nt++) {
            int col = wn * 64 + nt * 16 + ln;
            float bias = bxs[col];
            float g0 = gamma[col],       b0 = beta[col];
            float g1 = gamma[128 + col], b1 = beta[128 + col];
            float g2 = gamma[256 + col], b2 = beta[256 + col];
            int r0 = rowbase + wm * 64 + mt * 16 + lh * 4;
            #pragma unroll
            for (int rg = 0; rg < 4; rg++) {
                float zv = tanhf_fast(acc[mt][nt][rg] + bias);
                size_t idx = ((size_t)(r0 + rg) << 7) + col;
                z[idx]  = f2bf(zv);
                qq[idx] = f2bf(zv * g0 + b0);
                kq[idx] = f2bf(zv * g1 + b1);
                ql[idx] = f2bf(zv * g2 + b2);
            }
        }
}

// ---------------- vT = tanh(x @ Wve + bve)^T : bf16 [B][2048][4096] (256^2) ----------------
__global__ __launch_bounds__(512, 2) void k_vgemm(const u16* __restrict__ xb, const u16* __restrict__ WveT,
                                                  const float* __restrict__ bve, u16* __restrict__ vT) {
    __shared__ u16 As[2 * T256];
    __shared__ u16 Bs[2 * T256];
    const int tid = threadIdx.x;
    const int lane = tid & 63, w = tid >> 6;
    const int ln = lane & 15, lh = lane >> 4;
    const int wm = w >> 2, wn = w & 3;
    const int rowbase = xcd_swz(blockIdx.x, 128) * 256;
    const int colbase = blockIdx.y * 256;
    const u16* Ab = xb + (size_t)rowbase * 1024;
    const u16* Bb = WveT + (size_t)colbase * 1024;
    f4 acc[8][4] = {};
    gemm_pipe256<16>(
        [&](u16* a, u16* b, int t) {
            stage256x64(Ab + t * 64, 1024, a, tid);
            stage256x64(Bb + t * 64, 1024, b, tid);
        },
        As, Bs, wm, wn, ln, lh, acc);
    #pragma unroll
    for (int mt = 0; mt < 8; mt++)
        #pragma unroll
        for (int nt = 0; nt < 4; nt++) {
            int e = colbase + wn * 64 + nt * 16 + ln;
            float bias = bve[e];
            int r0 = rowbase + wm * 128 + mt * 16 + lh * 4;
            int bb = r0 >> 12, s0 = r0 & 4095;       // 4 consecutive s, same b
            us4 p;
            #pragma unroll
            for (int rg = 0; rg < 4; rg++) p[rg] = f2bf(tanhf_fast(acc[mt][nt][rg] + bias));
            *reinterpret_cast<us4*>(vT + (((size_t)bb * 2048 + e) << 12) + s0) = p;
        }
}

// ---------------- kvF[b][e][s] += vT[b][e][kseg] @ klinT[b][s][kseg] (pipelined 128^2, K-split x4) --------
__global__ __launch_bounds__(256) void k_kv(const u16* __restrict__ vT, const u16* __restrict__ klt,
                                            float* __restrict__ kvF) {
    __shared__ u16 As[2][128 * 64];
    __shared__ u16 Bs[2][128 * 64];
    const int tid = threadIdx.x;
    const int lane = tid & 63, w = tid >> 6;
    const int ln = lane & 15, lh = lane >> 4;
    const int wm = w >> 1, wn = w & 1;
    const int b = blockIdx.z;
    const int rowbase = blockIdx.x * 128;            // e
    const int kbase = blockIdx.y * 1024;             // pos segment
    const u16* Ab = vT + ((size_t)b * 2048 + rowbase) * 4096 + kbase;
    const u16* Bb = klt + ((size_t)b * 128) * 4096 + kbase;
    f4 acc[4][4] = {};
    gemm_pipe<16>(
        [&](u16* l, int t) { stage128x64(Ab + t * 64, 4096, l, w, lane); },
        [&](u16* l, int t) { stage128x64(Bb + t * 64, 4096, l, w, lane); },
        As[0], Bs[0], wm, wn, ln, lh, acc);
    #pragma unroll
    for (int mt = 0; mt < 4; mt++)
        #pragma unroll
        for (int nt = 0; nt < 4; nt++) {
            int s = wn * 64 + nt * 16 + ln;
            int e0 = rowbase + wm * 64 + mt * 16 + lh * 4;
            #pragma unroll
            for (int rg = 0; rg < 4; rg++)
                atomicAdd(&kvF[(((size_t)b * 2048 + e0 + rg) << 7) + s], acc[mt][nt][rg]);
        }
}

__global__ void k_kvcvt(const float* __restrict__ kvF, u16* __restrict__ kvT, int n) {
    int i = (blockIdx.x * blockDim.x + threadIdx.x) * 4;
    if (i < n) {
        float4 v = *reinterpret_cast<const float4*>(kvF + i);
        us4 o; o[0] = f2bf(v.x); o[1] = f2bf(v.y); o[2] = f2bf(v.z); o[3] = f2bf(v.w);
        *reinterpret_cast<us4*>(kvT + i) = o;
    }
}

// ---------------- a = relu(qq @ kq^T + rel_bias)^2 : bf16 [128][256][256] (pure GEMM) ----------------
__global__ __launch_bounds__(256) void k_a(const u16* __restrict__ qq, const u16* __restrict__ kq,
                                           const float* __restrict__ rel_bias, u16* __restrict__ a_out) {
    const int lane = threadIdx.x & 63, wid = threadIdx.x >> 6;
    const int ln = lane & 15, lh = lane >> 4;
    const int wm = wid >> 1, wn = wid & 1;
    const int ci = blockIdx.y;
    const int qbase = blockIdx.x * 128 + wm * 64;    // q rows within chunk
    const int nbase = wn * 128;                      // key cols within chunk
    const int rowbase = ci << 8;
    f4 acc[4][8] = {};
    const u16* qr[4];
    #pragma unroll
    for (int mt = 0; mt < 4; mt++) qr[mt] = qq + ((size_t)(rowbase + qbase + mt * 16 + ln) << 7);
    const u16* kr[8];
    #pragma unroll
    for (int nt = 0; nt < 8; nt++) kr[nt] = kq + ((size_t)(rowbase + nbase + nt * 16 + ln) << 7);
    #pragma unroll
    for (int kk = 0; kk < 128; kk += 32) {
        int k0 = kk + lh * 8;
        bf8 aq[4], ak[8];
        #pragma unroll
        for (int mt = 0; mt < 4; mt++) aq[mt] = *reinterpret_cast<const bf8*>(qr[mt] + k0);
        #pragma unroll
        for (int nt = 0; nt < 8; nt++) ak[nt] = *reinterpret_cast<const bf8*>(kr[nt] + k0);
        #pragma unroll
        for (int mt = 0; mt < 4; mt++)
            #pragma unroll
            for (int nt = 0; nt < 8; nt++)
                acc[mt][nt] = MFMA(aq[mt], ak[nt], acc[mt][nt]);
    }
    #pragma unroll
    for (int nt = 0; nt < 8; nt++) {
        int key = nbase + nt * 16 + ln;
        float rb = rel_bias[key];
        #pragma unroll
        for (int mt = 0; mt < 4; mt++) {
            int r0 = qbase + mt * 16 + lh * 4;
            #pragma unroll
            for (int rg = 0; rg < 4; rg++) {
                float v = acc[mt][nt][rg] + rb;
                v = fmaxf(v, 0.0f); v = v * v;
                a_out[((size_t)ci << 16) + ((size_t)(r0 + rg) << 8) + key] = f2bf(v);
            }
        }
    }
}

// ---------------- t2 = ql @ kv + a @ v : bf16 [32768][2048] (256^2, 6-tile pipeline) ----------------
__global__ __launch_bounds__(512, 2) void k_t1(const u16* __restrict__ ql, const u16* __restrict__ a_in,
                                               const u16* __restrict__ vT, const u16* __restrict__ kvT,
                                               u16* __restrict__ t1) {
    __shared__ u16 As[2 * T256];
    __shared__ u16 Bs[2 * T256];
    const int tid = threadIdx.x;
    const int lane = tid & 63, w = tid >> 6;
    const int ln = lane & 15, lh = lane >> 4;
    const int wm = w >> 2, wn = w & 3;
    const int ci = xcd_swz(blockIdx.x, 128);         // chunk == 256-row block
    const int rowbase = ci << 8;
    const int ebase = blockIdx.y * 256;
    const int b = ci >> 4, g = ci & 15;
    const u16* Aa = ql + (size_t)rowbase * 128;                       // phase a A (ld 128)
    const u16* Ba = kvT + ((size_t)(b * 2048 + ebase)) * 128;         // phase a B (ld 128)
    const u16* Ab = a_in + ((size_t)ci << 16);                        // phase b A (ld 256)
    const u16* Bb = vT + ((size_t)(b * 2048 + ebase)) * 4096 + (g << 8);  // phase b B (ld 4096)
    f4 acc[8][4] = {};
    gemm_pipe256<6>(
        [&](u16* a, u16* bl, int t) {
            if (t < 2) {
                stage256x64(Aa + t * 64, 128, a, tid);
                stage256x64(Ba + t * 64, 128, bl, tid);
            } else {
                stage256x64(Ab + (t - 2) * 64, 256, a, tid);
                stage256x64(Bb + (t - 2) * 64, 4096, bl, tid);
            }
        },
        As, Bs, wm, wn, ln, lh, acc);
    #pragma unroll
    for (int mt = 0; mt < 8; mt++)
        #pragma unroll
        for (int nt = 0; nt < 4; nt++) {
            int e = ebase + wn * 64 + nt * 16 + ln;
            int r0 = rowbase + wm * 128 + mt * 16 + lh * 4;
            #pragma unroll
            for (int rg = 0; rg < 4; rg++)
                t1[((size_t)(r0 + rg) << 11) + e] = f2bf(acc[mt][nt][rg]);
        }
}

// ---------------- t1 = tanh(x @ Wue + bue) * t2 (in place, 256^2) ----------------
__global__ __launch_bounds__(512, 2) void k_u(const u16* __restrict__ xb, const u16* __restrict__ WueT,
                                              const float* __restrict__ bue, u16* t1) {
    __shared__ u16 As[2 * T256];
    __shared__ u16 Bs[2 * T256];
    const int tid = threadIdx.x;
    const int lane = tid & 63, w = tid >> 6;
    const int ln = lane & 15, lh = lane >> 4;
    const int wm = w >> 2, wn = w & 3;
    const int rowbase = xcd_swz(blockIdx.x, 128) * 256;
    const int colbase = blockIdx.y * 256;
    const u16* Ab = xb + (size_t)rowbase * 1024;
    const u16* Bb = WueT + (size_t)colbase * 1024;
    f4 acc[8][4] = {};
    gemm_pipe256<16>(
        [&](u16* a, u16* b, int t) {
            stage256x64(Ab + t * 64, 1024, a, tid);
            stage256x64(Bb + t * 64, 1024, b, tid);
        },
        As, Bs, wm, wn, ln, lh, acc);
    #pragma unroll
    for (int mt = 0; mt < 8; mt++)
        #pragma unroll
        for (int nt = 0; nt < 4; nt++) {
            int e = colbase + wn * 64 + nt * 16 + ln;
            float bias = bue[e];
            int r0 = rowbase + wm * 128 + mt * 16 + lh * 4;
            #pragma unroll
            for (int rg = 0; rg < 4; rg++) {
                size_t idx = ((size_t)(r0 + rg) << 11) + e;
                float t = bf2f(t1[idx]);
                float u = tanhf_fast(acc[mt][nt][rg] + bias);
                t1[idx] = f2bf(u * t);
            }
        }
}

// ---------------- out = t1 @ Wod + bod -> [s][b][d] f32 (256^2) ----------------
__global__ __launch_bounds__(512, 2) void k_o(const u16* __restrict__ t1, const u16* __restrict__ WodT,
                                              const float* __restrict__ bod, float* __restrict__ out) {
    __shared__ u16 As[2 * T256];
    __shared__ u16 Bs[2 * T256];
    const int tid = threadIdx.x;
    const int lane = tid & 63, w = tid >> 6;
    const int ln = lane & 15, lh = lane >> 4;
    const int wm = w >> 2, wn = w & 3;
    const int rowbase = xcd_swz(blockIdx.x, 128) * 256;
    const int colbase = blockIdx.y * 256;
    const u16* Ab = t1 + (size_t)rowbase * 2048;
    const u16* Bb = WodT + (size_t)colbase * 2048;
    f4 acc[8][4] = {};
    gemm_pipe256<32>(
        [&](u16* a, u16* b, int t) {
            stage256x64(Ab + t * 64, 2048, a, tid);
            stage256x64(Bb + t * 64, 2048, b, tid);
        },
        As, Bs, wm, wn, ln, lh, acc);
    #pragma unroll
    for (int mt = 0; mt < 8; mt++)
        #pragma unroll
        for (int nt = 0; nt < 4; nt++) {
            int d = colbase + wn * 64 + nt * 16 + ln;
            float bias = bod[d];
            int r0 = rowbase + wm * 128 + mt * 16 + lh * 4;
            #pragma unroll
            for (int rg = 0; rg < 4; rg++) {
                int r = r0 + rg;
                int s = r & 4095, bb = r >> 12;
                out[((size_t)(s * 8 + bb) << 10) + d] = acc[mt][nt][rg] + bias;
            }
        }
}

extern "C" void kernel_launch(void* const* d_in, const int* in_sizes, int n_in,
                              void* d_out, int out_size, void* d_ws, size_t ws_size,
                              hipStream_t stream) {
    const float* value = (const float*)d_in[2];
    const float* Wxs = (const float*)d_in[3];  const float* bxs = (const float*)d_in[4];
    const float* Wve = (const float*)d_in[5];  const float* bve = (const float*)d_in[6];
    const float* Wue = (const float*)d_in[7];  const float* bue = (const float*)d_in[8];
    const float* Wod = (const float*)d_in[9];  const float* bod = (const float*)d_in[10];
    const float* rel_bias = (const float*)d_in[11];
    const float* gamma = (const float*)d_in[12];
    const float* beta  = (const float*)d_in[13];
    float* out = (float*)d_out;

    char* ws = (char*)d_ws;
    u16* xb   = (u16*)(ws + WS_XB);
    u16* WxsT = (u16*)(ws + WS_WXST);
    u16* WveT = (u16*)(ws + WS_WVET);
    u16* WueT = (u16*)(ws + WS_WUET);
    u16* WodT = (u16*)(ws + WS_WODT);
    u16* kvT  = (u16*)(ws + WS_KVT);
    u16* a    = (u16*)(ws + WS_A);
    u16* ql   = (u16*)(ws + WS_QL);
    u16* vT   = (u16*)(ws + WS_VT);
    u16* t1   = (u16*)(ws + WS_T1);
    u16* z    = (u16*)(ws + WS_Z);
    u16* klt  = (u16*)(ws + WS_KLT);
    u16* qq   = (u16*)(ws + WS_QQ);
    u16* kq   = (u16*)(ws + WS_KQ);
    float* kvF = (float*)(ws + WS_KVF);

    // conversions
    k_cvt_x<<<32768, 256, 0, stream>>>(value, xb);
    k_transpose<<<dim3(4, 32),  256, 0, stream>>>(Wxs, WxsT, 1024, 128);
    k_transpose<<<dim3(64, 32), 256, 0, stream>>>(Wve, WveT, 1024, 2048);
    k_transpose<<<dim3(64, 32), 256, 0, stream>>>(Wue, WueT, 1024, 2048);
    k_transpose<<<dim3(32, 64), 256, 0, stream>>>(Wod, WodT, 2048, 1024);
    // z + affine variants (pipelined 128^2)
    k_zgemm<<<256, 256, 0, stream>>>(xb, WxsT, bxs, gamma, beta, z, qq, kq, ql);
    // k_lin transposed
    k_klinT<<<dim3(1024, 4), 256, 0, stream>>>(z, gamma, beta, klt);
    // v (256^2)
    k_vgemm<<<dim3(128, 8), 512, 0, stream>>>(xb, WveT, bve, vT);
    // kv (pipelined 128^2, K-split x4 atomics)
    hipMemsetAsync(kvF, 0, (size_t)8 * 2048 * 128 * 4, stream);
    k_kv<<<dim3(16, 4, 8), 256, 0, stream>>>(vT, klt, kvF);
    k_kvcvt<<<2048, 256, 0, stream>>>(kvF, kvT, 8 * 2048 * 128);
    // quadratic attention scores (pure GEMM)
    k_a<<<dim3(2, 128), 256, 0, stream>>>(qq, kq, rel_bias, a);
    // t2 = v_quad + v_lin (256^2, 6 tiles)
    k_t1<<<dim3(128, 8), 512, 0, stream>>>(ql, a, vT, kvT, t1);
    // t1 = tanh(u) * t2 (256^2, in place)
    k_u<<<dim3(128, 8), 512, 0, stream>>>(xb, WueT, bue, t1);
    // out (256^2)
    k_o<<<dim3(128, 4), 512, 0, stream>>>(t1, WodT, bod, out);
}